// Round 3
// baseline (971.759 us; speedup 1.0000x reference)
//
#include <hip/hip_runtime.h>
#include <cstdint>

// PointTransformerLayer, MI355X. Folded-weight formulation:
//   M  = Wt2@Wt1 (64x3)          delta = relu(M . rel)
//   G  = Wg2@Wg1 (64x64)         g = relu(Gphi[n] - Gpsi[idx] + G.delta)
//   GW1= G@Wlin[0:64], GW2 = G@Wlin[64:128], alpha = Wlin[128:192] @ f
// KNN: fp32 FMA prefilter keeps top-24 PER SEGMENT (margin >> FMA-vs-noFMA
//      skew ~1e-5), then NUMPY-FP32-BIT-EXACT re-rank of the 48 survivors:
//      d2 = (sq_n + sq_m) - 2*dot with sequential no-FMA fp32 (matching
//      np.sum(c*c,axis=1) and naive np.einsum c-order), ties by lowest
//      index (= stable top_k). Round-2 evidence: float64-exact selection
//      mismatched identically at MKEEP=16 and 24 => ref selection is fp32.

#define NPT 8192
typedef unsigned long long u64;
typedef unsigned int u32;

__device__ __forceinline__ float rlf(float v, int lane) {
  return __int_as_float(__builtin_amdgcn_readlane(__float_as_int(v), lane));
}

// ---------- fold1: G = Wg2@Wg1 (64x64); M = Wt2@Wt1 (64x3, row + colT) ----
__global__ __launch_bounds__(256) void fold1_k(
    const float* __restrict__ wg1, const float* __restrict__ wg2,
    const float* __restrict__ wt1, const float* __restrict__ wt2,
    float* __restrict__ G, float* __restrict__ Mrow, float* __restrict__ McT) {
  int t = blockIdx.x * 256 + threadIdx.x;
  if (t < 4096) {
    int o = t >> 6, c = t & 63;
    float acc = 0.f;
    for (int cp = 0; cp < 64; ++cp) acc = fmaf(wg2[o * 64 + cp], wg1[cp * 64 + c], acc);
    G[o * 64 + c] = acc;
  } else if (t < 4096 + 192) {
    int i = t - 4096;
    int o = i / 3, j = i - o * 3;
    float acc = 0.f;
    for (int c = 0; c < 64; ++c) acc = fmaf(wt2[o * 64 + c], wt1[c * 3 + j], acc);
    Mrow[o * 3 + j] = acc;
    McT[j * 64 + o] = acc;
  }
}

// ---------- fold2: wcomb rows [0:64)=G@W1, [64:128)=G@W2, [128:192)=Wlin ---
__global__ __launch_bounds__(256) void fold2_k(
    const float* __restrict__ G, const float* __restrict__ wl,
    float* __restrict__ wcomb) {
  int t = blockIdx.x * 256 + threadIdx.x;  // 12288
  int o = t >> 6, c = t & 63;
  float acc = 0.f;
  if (o < 64) {
    for (int cp = 0; cp < 64; ++cp) acc = fmaf(G[o * 64 + cp], wl[cp * 64 + c], acc);
  } else if (o < 128) {
    for (int cp = 0; cp < 64; ++cp) acc = fmaf(G[(o - 64) * 64 + cp], wl[(64 + cp) * 64 + c], acc);
  } else {
    acc = wl[o * 64 + c];
  }
  wcomb[o * 64 + c] = acc;
}

// ---------- pack coords as float4 (x,y,z,sq) with NP-EXACT sq -------------
// sq must match np.sum(coords*coords, axis=1): ((x*x + y*y) + z*z),
// round-to-nearest each op, NO FMA contraction.
__global__ __launch_bounds__(256) void pack_k(const float* __restrict__ coords,
                                              float4* __restrict__ pack) {
  int g = blockIdx.x * 256 + threadIdx.x;  // 32768
  int b = g >> 13, n = g & (NPT - 1);
  const float* c = coords + (size_t)b * 3 * NPT;
  float x = c[n], y = c[NPT + n], z = c[2 * NPT + n];
  float sq = __fadd_rn(__fadd_rn(__fmul_rn(x, x), __fmul_rn(y, y)), __fmul_rn(z, z));
  pack[g] = make_float4(x, y, z, sq);
}

// ---------- KNN prefilter: top-24 per 4096-candidate segment --------------
// Selection key here is fast FMA fp32 (approx); 8 extra slots of margin
// guarantee recall of the np-fp32-exact top-16 (skew <= ~1e-5).
#define MKEEP 24
#define CAP 49
#define DRAIN_AT 33
__global__ __launch_bounds__(128) void knn_k(const float4* __restrict__ pack,
                                             u64* __restrict__ part) {
  __shared__ u64 buf[128 * CAP];
  int tid = threadIdx.x;
  int b = blockIdx.y, seg = blockIdx.z;
  int n = blockIdx.x * 128 + tid;
  const float4* pk = pack + (size_t)b * NPT;
  float4 q = pk[n];
  float qsq = q.w;
  u64 arr[MKEEP];
#pragma unroll
  for (int j = 0; j < MKEEP; ++j) arr[j] = ~0ull;
  u32 Thi = 0xFFFFFFFFu;
  int cnt = 0;
  int m0 = seg * 4096;
  int lane = tid & 63;
  float4 cur = pk[m0 + lane];
  for (int mc = m0; mc < m0 + 4096; mc += 64) {
    int nm = (mc + 64 < m0 + 4096) ? (mc + 64 + lane) : (m0 + lane);
    float4 nxt = pk[nm];  // double-buffered chunk (hides load latency)
    for (int sub = 0; sub < 4; ++sub) {
      int base = sub * 16;
#pragma unroll
      for (int jj = 0; jj < 16; ++jj) {
        int j = base + jj;
        float cx = rlf(cur.x, j), cy = rlf(cur.y, j), cz = rlf(cur.z, j), cq = rlf(cur.w, j);
        float dot = fmaf(q.z, cz, fmaf(q.y, cy, q.x * cx));
        float d2 = fmaf(-2.f, dot, qsq + cq);
        d2 = fmaxf(d2, 0.f);  // keep monotone u32 order (self ~0)
        u32 hi = __float_as_uint(d2);
        if (hi <= Thi) {  // conservative guard vs current 24th-best
          buf[tid * CAP + cnt] = ((u64)hi << 32) | (u32)(mc + j);
          ++cnt;
        }
      }
      if (__ballot(cnt >= DRAIN_AT)) {  // wave-parallel amortized maintenance
        for (int t2 = 0;; ++t2) {
          if (!__ballot(t2 < cnt)) break;
          if (t2 < cnt) {
            u64 key = buf[tid * CAP + t2];
            if (key < arr[MKEEP - 1]) {
#pragma unroll
              for (int qq = 0; qq < MKEEP; ++qq) {
                bool cs = key < arr[qq];
                u64 tmp = arr[qq];
                arr[qq] = cs ? key : tmp;
                key = cs ? tmp : key;
              }
            }
          }
        }
        cnt = 0;
        Thi = (u32)(arr[MKEEP - 1] >> 32);
      }
    }
    cur = nxt;
  }
  for (int t2 = 0;; ++t2) {  // final drain
    if (!__ballot(t2 < cnt)) break;
    if (t2 < cnt) {
      u64 key = buf[tid * CAP + t2];
      if (key < arr[MKEEP - 1]) {
#pragma unroll
        for (int qq = 0; qq < MKEEP; ++qq) {
          bool cs = key < arr[qq];
          u64 tmp = arr[qq];
          arr[qq] = cs ? key : tmp;
          key = cs ? tmp : key;
        }
      }
    }
  }
  size_t g = (size_t)b * NPT + n;
#pragma unroll
  for (int j = 0; j < MKEEP; ++j)
    part[g * (2 * MKEEP) + (size_t)seg * MKEEP + j] = arr[j];
}

// ---------- numpy-fp32-bit-exact re-rank of the 48 survivors --------------
// d2 = fl(fl(sq_n + sq_m) - fl(2*dot)),  dot = fl(fl(fl(xn*xm)+fl(yn*ym))+fl(zn*zm))
// No FMA anywhere. Negative d2 legal (near-dup pairs); float compares.
// Ties by lowest index == stable top_k.
__global__ __launch_bounds__(256) void refine_k(const float4* __restrict__ pack,
                                                const u64* __restrict__ part,
                                                int* __restrict__ idxk) {
  int g = blockIdx.x * 256 + threadIdx.x;  // 32768
  int b = g >> 13;
  const float4* pk = pack + (size_t)b * NPT;
  float4 q = pk[g & (NPT - 1)];
  float qx = q.x, qy = q.y, qz = q.z, qs = q.w;
  float bd[16];
  int bi[16];
#pragma unroll
  for (int j = 0; j < 16; ++j) { bd[j] = 1e30f; bi[j] = 0x7FFFFFFF; }
  const u64* p = part + (size_t)g * (2 * MKEEP);
  for (int j = 0; j < 2 * MKEEP; ++j) {
    u64 key = p[j];
    int m = (int)(u32)(key & 0xFFFFFFFFull);
    float4 pm = pk[m];
    float dot = __fadd_rn(__fadd_rn(__fmul_rn(qx, pm.x), __fmul_rn(qy, pm.y)),
                          __fmul_rn(qz, pm.z));
    float kd = __fsub_rn(__fadd_rn(qs, pm.w), __fmul_rn(2.0f, dot));
    int ki = m;
#pragma unroll
    for (int qq = 0; qq < 16; ++qq) {
      bool cs = (kd < bd[qq]) || (kd == bd[qq] && ki < bi[qq]);
      float td = bd[qq];
      int ti = bi[qq];
      bd[qq] = cs ? kd : td;
      bi[qq] = cs ? ki : ti;
      kd = cs ? td : kd;
      ki = cs ? ti : ki;
    }
  }
#pragma unroll
  for (int j = 0; j < 16; ++j) idxk[(size_t)g * 16 + j] = bi[j];
}

// ---------- feat: feat3T[P][0:64)=Gphi, [64:128)=Gpsi, [128:192)=alpha ----
__global__ __launch_bounds__(256) void feat_k(const float* __restrict__ features,
                                              const float* __restrict__ wcomb,
                                              float* __restrict__ feat3T) {
  int t = blockIdx.x * 256 + threadIdx.x;  // 65536
  int half = t >> 15;
  int P = t & 32767;
  int b = P >> 13, n = P & (NPT - 1);
  const float* fin = features + (size_t)b * 64 * NPT + n;
  float f[64];
#pragma unroll
  for (int c = 0; c < 64; ++c) f[c] = fin[(size_t)c * NPT];
  const float* W = wcomb + half * 96 * 64;
  float* op = feat3T + (size_t)P * 192 + half * 96;
  for (int r4 = 0; r4 < 24; ++r4) {
    float a0 = 0.f, a1 = 0.f, a2 = 0.f, a3 = 0.f;
    const float* w0 = W + (r4 * 4) * 64;
#pragma unroll
    for (int c = 0; c < 64; ++c) {
      a0 = fmaf(w0[c], f[c], a0);
      a1 = fmaf(w0[64 + c], f[c], a1);
      a2 = fmaf(w0[128 + c], f[c], a2);
      a3 = fmaf(w0[192 + c], f[c], a3);
    }
    *(float4*)(op + r4 * 4) = make_float4(a0, a1, a2, a3);
  }
}

// ---------- attention: wave = 4 points, lane=(p,k); LDS transpose 64x66 ---
#define SST 66
__global__ __launch_bounds__(128) void attn_k(
    const float4* __restrict__ pack, const int* __restrict__ idxk,
    const float* __restrict__ feat3T, const float* __restrict__ G,
    const float* __restrict__ Mrow, const float* __restrict__ McT,
    float* __restrict__ out) {
  __shared__ float sb[2 * 64 * SST];
  int tid = threadIdx.x;
  int w = tid >> 6, l = tid & 63;
  float* S = sb + w * 64 * SST;
  int wg = blockIdx.x * 2 + w;
  int Pb = wg * 4;
  int b = Pb >> 13;
  int nb0 = Pb & (NPT - 1);
  int p = l >> 4;
  const float4* pkb = pack + (size_t)b * NPT;
  int idxv = idxk[(size_t)Pb * 16 + l];  // lane l = (point p, neighbor k)
  float4 own = pkb[nb0 + p];
  float4 nbr = pkb[idxv];
  float rx = own.x - nbr.x, ry = own.y - nbr.y, rz = own.z - nbr.z;
  float delta[64];
#pragma unroll
  for (int o = 0; o < 64; ++o)
    delta[o] = fmaxf(fmaf(Mrow[o * 3 + 2], rz, fmaf(Mrow[o * 3 + 1], ry, Mrow[o * 3] * rx)), 0.f);
  {  // pp = Gphi(own) - Gpsi(neighbor) staged to LDS (lane-row, stride 66)
    const float* phir = feat3T + (size_t)(Pb + p) * 192;
    const float* psir = feat3T + ((size_t)b * NPT + idxv) * 192 + 64;
#pragma unroll
    for (int o4 = 0; o4 < 16; ++o4) {
      float4 ph = *(const float4*)(phir + o4 * 4);
      float4 ps = *(const float4*)(psir + o4 * 4);
      int ad = l * SST + o4 * 4;
      S[ad] = ph.x - ps.x;
      S[ad + 1] = ph.y - ps.y;
      S[ad + 2] = ph.z - ps.z;
      S[ad + 3] = ph.w - ps.w;
    }
  }
  // g = relu(pp + G.delta): uniform G rows via s_load, two acc chains
  for (int o = 0; o < 64; o += 2) {
    const float* g0 = G + o * 64;
    float a0 = 0.f, a1 = 0.f;
#pragma unroll
    for (int c = 0; c < 64; ++c) {
      a0 = fmaf(g0[c], delta[c], a0);
      a1 = fmaf(g0[64 + c], delta[c], a1);
    }
    int ad = l * SST + o;
    float pp0 = S[ad], pp1 = S[ad + 1];
    S[ad] = fmaxf(pp0 + a0, 0.f);
    S[ad + 1] = fmaxf(pp1 + a1, 0.f);
  }
  __syncthreads();  // ordering for cross-lane LDS reads below
  // read side: lane l = channel, loop over the wave's 4 points
  float m0v = McT[l], m1v = McT[64 + l], m2v = McT[128 + l];
#pragma unroll 1
  for (int j = 0; j < 4; ++j) {
    int nj = nb0 + j;
    float4 ownq = pkb[nj];
    float gv[16], dl[16];
    int sidx[16];
    float mx = -1e30f;
#pragma unroll
    for (int r = 0; r < 16; ++r) {
      int si = __builtin_amdgcn_readlane(idxv, j * 16 + r);
      sidx[r] = si;
      float4 nbq = pkb[si];
      float rxq = ownq.x - nbq.x, ryq = ownq.y - nbq.y, rzq = ownq.z - nbq.z;
      dl[r] = fmaxf(fmaf(m2v, rzq, fmaf(m1v, ryq, m0v * rxq)), 0.f);
      gv[r] = S[(j * 16 + r) * SST + l];
      mx = fmaxf(mx, gv[r]);
    }
    float s = 0.f;
#pragma unroll
    for (int r = 0; r < 16; ++r) {
      float e = expf(gv[r] - mx);
      gv[r] = e;
      s += e;
    }
    float inv = 1.0f / s;
    float acc = 0.f;
#pragma unroll
    for (int r = 0; r < 16; ++r) {
      float al = feat3T[((size_t)b * NPT + sidx[r]) * 192 + 128 + l];
      acc = fmaf(gv[r] * inv, al + dl[r], acc);
    }
    out[(size_t)b * 64 * NPT + (size_t)l * NPT + nj] = acc;
  }
}

extern "C" void kernel_launch(void* const* d_in, const int* in_sizes, int n_in,
                              void* d_out, int out_size, void* d_ws, size_t ws_size,
                              hipStream_t stream) {
  const float* features = (const float*)d_in[0];
  const float* coords = (const float*)d_in[1];
  const float* w_lin = (const float*)d_in[2];
  const float* w_t1 = (const float*)d_in[3];
  const float* w_t2 = (const float*)d_in[4];
  const float* w_g1 = (const float*)d_in[5];
  const float* w_g2 = (const float*)d_in[6];
  float* out = (float*)d_out;
  char* ws = (char*)d_ws;
  // workspace layout (~27.9 MB total; part overlaps feat3T, consumed first)
  float4* pack = (float4*)ws;                   // 524288 B
  float* G = (float*)(ws + 524288);             // 16384 B
  float* Mrow = (float*)(ws + 540672);          // 768 B
  float* McT = (float*)(ws + 541440);           // 768 B
  float* wcomb = (float*)(ws + 542208);         // 49152 B
  int* idxk = (int*)(ws + 591360);              // 2 MB
  float* feat3T = (float*)(ws + 2688512);       // 24 MB
  u64* part = (u64*)(ws + 2688512);             // 12.6 MB (overlap, freed by refine)

  fold1_k<<<17, 256, 0, stream>>>(w_g1, w_g2, w_t1, w_t2, G, Mrow, McT);
  fold2_k<<<48, 256, 0, stream>>>(G, w_lin, wcomb);
  pack_k<<<128, 256, 0, stream>>>(coords, pack);
  knn_k<<<dim3(64, 4, 2), 128, 0, stream>>>(pack, part);
  refine_k<<<128, 256, 0, stream>>>(pack, part, idxk);
  feat_k<<<256, 256, 0, stream>>>(features, wcomb, feat3T);  // after refine: reuses part region
  attn_k<<<4096, 128, 0, stream>>>(pack, idxk, feat3T, G, Mrow, McT, out);
}

// Round 4
// 957.767 us; speedup vs baseline: 1.0146x; 1.0146x over previous
//
#include <hip/hip_runtime.h>
#include <cstdint>

// PointTransformerLayer, MI355X. Folded-weight formulation:
//   M  = Wt2@Wt1 (64x3)          delta = relu(M . rel)
//   G  = Wg2@Wg1 (64x64)         g = relu(Gphi[n] - Gpsi[idx] + G.delta)
//   GW1= G@Wlin[0:64], GW2 = G@Wlin[64:128], alpha = Wlin[128:192] @ f
// KNN: fp32 FMA prefilter, top-24 per 2048-candidate segment (S=4), then
//      NUMPY-FP32-BIT-EXACT re-rank of the 96 surviving indices (no-FMA
//      sequential fp32 d2, ties by lowest index = stable top_k).
// R3 evidence: passed at absmax 2e-3; knn_k 557us with Occupancy 9%,
// VALUBusy 38%, 489k LDS bank conflicts (queue stride 98 dw = 4-way).
// R4: 4x waves (S=4, 64-thr blocks), queue transposed to [slot][lane]
// (2-way = free), CAP 49->24 (12KB LDS), part stores idx-only.

#define NPT 8192
typedef unsigned long long u64;
typedef unsigned int u32;

__device__ __forceinline__ float rlf(float v, int lane) {
  return __int_as_float(__builtin_amdgcn_readlane(__float_as_int(v), lane));
}

// ---------- fold1: G = Wg2@Wg1 (64x64); M = Wt2@Wt1 (64x3, row + colT) ----
__global__ __launch_bounds__(256) void fold1_k(
    const float* __restrict__ wg1, const float* __restrict__ wg2,
    const float* __restrict__ wt1, const float* __restrict__ wt2,
    float* __restrict__ G, float* __restrict__ Mrow, float* __restrict__ McT) {
  int t = blockIdx.x * 256 + threadIdx.x;
  if (t < 4096) {
    int o = t >> 6, c = t & 63;
    float acc = 0.f;
    for (int cp = 0; cp < 64; ++cp) acc = fmaf(wg2[o * 64 + cp], wg1[cp * 64 + c], acc);
    G[o * 64 + c] = acc;
  } else if (t < 4096 + 192) {
    int i = t - 4096;
    int o = i / 3, j = i - o * 3;
    float acc = 0.f;
    for (int c = 0; c < 64; ++c) acc = fmaf(wt2[o * 64 + c], wt1[c * 3 + j], acc);
    Mrow[o * 3 + j] = acc;
    McT[j * 64 + o] = acc;
  }
}

// ---------- fold2: wcomb rows [0:64)=G@W1, [64:128)=G@W2, [128:192)=Wlin ---
__global__ __launch_bounds__(256) void fold2_k(
    const float* __restrict__ G, const float* __restrict__ wl,
    float* __restrict__ wcomb) {
  int t = blockIdx.x * 256 + threadIdx.x;  // 12288
  int o = t >> 6, c = t & 63;
  float acc = 0.f;
  if (o < 64) {
    for (int cp = 0; cp < 64; ++cp) acc = fmaf(G[o * 64 + cp], wl[cp * 64 + c], acc);
  } else if (o < 128) {
    for (int cp = 0; cp < 64; ++cp) acc = fmaf(G[(o - 64) * 64 + cp], wl[(64 + cp) * 64 + c], acc);
  } else {
    acc = wl[o * 64 + c];
  }
  wcomb[o * 64 + c] = acc;
}

// ---------- pack coords as float4 (x,y,z,sq) with NP-EXACT sq -------------
// sq matches np.sum(coords*coords, axis=1): ((x*x + y*y) + z*z), no FMA.
__global__ __launch_bounds__(256) void pack_k(const float* __restrict__ coords,
                                              float4* __restrict__ pack) {
  int g = blockIdx.x * 256 + threadIdx.x;  // 32768
  int b = g >> 13, n = g & (NPT - 1);
  const float* c = coords + (size_t)b * 3 * NPT;
  float x = c[n], y = c[NPT + n], z = c[2 * NPT + n];
  float sq = __fadd_rn(__fadd_rn(__fmul_rn(x, x), __fmul_rn(y, y)), __fmul_rn(z, z));
  pack[g] = make_float4(x, y, z, sq);
}

// ---------- KNN prefilter: top-24 per 2048-candidate segment --------------
// FMA fp32 key (approx); 8 extra slots of margin guarantee recall of the
// np-fp32-exact top-16 (key skew ~1e-5 << order-stat gaps ~1e-3).
#define MKEEP 24
#define SEGSZ 2048
#define NSEG 4
#define CAP 24
#define DRAIN_AT 8
__global__ __launch_bounds__(64) void knn_k(const float4* __restrict__ pack,
                                            u32* __restrict__ part) {
  __shared__ u64 buf[CAP * 64];  // [slot][lane]: bank = 2*lane, conflict-free
  int tid = threadIdx.x;         // == lane (64-thread block, wave-synchronous)
  int b = blockIdx.y, seg = blockIdx.z;
  int n = blockIdx.x * 64 + tid;
  const float4* pk = pack + (size_t)b * NPT;
  float4 q = pk[n];
  float qsq = q.w;
  u64 arr[MKEEP];
#pragma unroll
  for (int j = 0; j < MKEEP; ++j) arr[j] = ~0ull;
  u32 Thi = 0xFFFFFFFFu;
  int cnt = 0;
  int m0 = seg * SEGSZ;
  float4 cur = pk[m0 + tid];
  for (int mc = m0; mc < m0 + SEGSZ; mc += 64) {
    int nm = (mc + 64 < m0 + SEGSZ) ? (mc + 64 + tid) : (m0 + tid);
    float4 nxt = pk[nm];  // double-buffered chunk (hides load latency)
    for (int sub = 0; sub < 4; ++sub) {
      int base = sub * 16;
#pragma unroll
      for (int jj = 0; jj < 16; ++jj) {
        int j = base + jj;
        float cx = rlf(cur.x, j), cy = rlf(cur.y, j), cz = rlf(cur.z, j), cq = rlf(cur.w, j);
        float dot = fmaf(q.z, cz, fmaf(q.y, cy, q.x * cx));
        float d2 = fmaf(-2.f, dot, qsq + cq);
        d2 = fmaxf(d2, 0.f);  // keep monotone u32 order (self ~0)
        u32 hi = __float_as_uint(d2);
        if (hi <= Thi) {  // conservative guard vs current 24th-best
          buf[cnt * 64 + tid] = ((u64)hi << 32) | (u32)(mc + j);
          ++cnt;
        }
      }
      if (__ballot(cnt >= DRAIN_AT)) {  // wave-parallel amortized maintenance
        for (int t2 = 0;; ++t2) {
          if (!__ballot(t2 < cnt)) break;
          if (t2 < cnt) {
            u64 key = buf[t2 * 64 + tid];
            if (key < arr[MKEEP - 1]) {
#pragma unroll
              for (int qq = 0; qq < MKEEP; ++qq) {
                bool cs = key < arr[qq];
                u64 tmp = arr[qq];
                arr[qq] = cs ? key : tmp;
                key = cs ? tmp : key;
              }
            }
          }
        }
        cnt = 0;
        Thi = (u32)(arr[MKEEP - 1] >> 32);
      }
    }
    cur = nxt;
  }
  for (int t2 = 0;; ++t2) {  // final drain
    if (!__ballot(t2 < cnt)) break;
    if (t2 < cnt) {
      u64 key = buf[t2 * 64 + tid];
      if (key < arr[MKEEP - 1]) {
#pragma unroll
        for (int qq = 0; qq < MKEEP; ++qq) {
          bool cs = key < arr[qq];
          u64 tmp = arr[qq];
          arr[qq] = cs ? key : tmp;
          key = cs ? tmp : key;
        }
      }
    }
  }
  size_t g = (size_t)b * NPT + n;
#pragma unroll
  for (int j = 0; j < MKEEP; ++j)
    part[g * (NSEG * MKEEP) + (size_t)seg * MKEEP + j] = (u32)(arr[j] & 0xFFFFFFFFull);
}

// ---------- numpy-fp32-bit-exact re-rank of the 96 survivors --------------
// d2 = fl(fl(sq_n+sq_m) - fl(2*dot)), dot sequential no-FMA. Negative d2
// legal; float compares; ties by lowest index == stable top_k.
__global__ __launch_bounds__(256) void refine_k(const float4* __restrict__ pack,
                                                const u32* __restrict__ part,
                                                int* __restrict__ idxk) {
  int g = blockIdx.x * 256 + threadIdx.x;  // 32768
  int b = g >> 13;
  const float4* pk = pack + (size_t)b * NPT;
  float4 q = pk[g & (NPT - 1)];
  float qx = q.x, qy = q.y, qz = q.z, qs = q.w;
  float bd[16];
  int bi[16];
#pragma unroll
  for (int j = 0; j < 16; ++j) { bd[j] = 1e30f; bi[j] = 0x7FFFFFFF; }
  const u32* p = part + (size_t)g * (NSEG * MKEEP);
  for (int j = 0; j < NSEG * MKEEP; ++j) {
    int m = (int)p[j];
    float4 pm = pk[m];
    float dot = __fadd_rn(__fadd_rn(__fmul_rn(qx, pm.x), __fmul_rn(qy, pm.y)),
                          __fmul_rn(qz, pm.z));
    float kd = __fsub_rn(__fadd_rn(qs, pm.w), __fmul_rn(2.0f, dot));
    int ki = m;
    if (kd < bd[15] || (kd == bd[15] && ki < bi[15])) {  // guarded chain
#pragma unroll
      for (int qq = 0; qq < 16; ++qq) {
        bool cs = (kd < bd[qq]) || (kd == bd[qq] && ki < bi[qq]);
        float td = bd[qq];
        int ti = bi[qq];
        bd[qq] = cs ? kd : td;
        bi[qq] = cs ? ki : ti;
        kd = cs ? td : kd;
        ki = cs ? ti : ki;
      }
    }
  }
#pragma unroll
  for (int j = 0; j < 16; ++j) idxk[(size_t)g * 16 + j] = bi[j];
}

// ---------- feat: feat3T[P][0:64)=Gphi, [64:128)=Gpsi, [128:192)=alpha ----
__global__ __launch_bounds__(256) void feat_k(const float* __restrict__ features,
                                              const float* __restrict__ wcomb,
                                              float* __restrict__ feat3T) {
  int t = blockIdx.x * 256 + threadIdx.x;  // 65536
  int half = t >> 15;
  int P = t & 32767;
  int b = P >> 13, n = P & (NPT - 1);
  const float* fin = features + (size_t)b * 64 * NPT + n;
  float f[64];
#pragma unroll
  for (int c = 0; c < 64; ++c) f[c] = fin[(size_t)c * NPT];
  const float* W = wcomb + half * 96 * 64;
  float* op = feat3T + (size_t)P * 192 + half * 96;
  for (int r4 = 0; r4 < 24; ++r4) {
    float a0 = 0.f, a1 = 0.f, a2 = 0.f, a3 = 0.f;
    const float* w0 = W + (r4 * 4) * 64;
#pragma unroll
    for (int c = 0; c < 64; ++c) {
      a0 = fmaf(w0[c], f[c], a0);
      a1 = fmaf(w0[64 + c], f[c], a1);
      a2 = fmaf(w0[128 + c], f[c], a2);
      a3 = fmaf(w0[192 + c], f[c], a3);
    }
    *(float4*)(op + r4 * 4) = make_float4(a0, a1, a2, a3);
  }
}

// ---------- attention: wave = 4 points, lane=(p,k); LDS transpose 64x66 ---
#define SST 66
__global__ __launch_bounds__(128) void attn_k(
    const float4* __restrict__ pack, const int* __restrict__ idxk,
    const float* __restrict__ feat3T, const float* __restrict__ G,
    const float* __restrict__ Mrow, const float* __restrict__ McT,
    float* __restrict__ out) {
  __shared__ float sb[2 * 64 * SST];
  int tid = threadIdx.x;
  int w = tid >> 6, l = tid & 63;
  float* S = sb + w * 64 * SST;
  int wg = blockIdx.x * 2 + w;
  int Pb = wg * 4;
  int b = Pb >> 13;
  int nb0 = Pb & (NPT - 1);
  int p = l >> 4;
  const float4* pkb = pack + (size_t)b * NPT;
  int idxv = idxk[(size_t)Pb * 16 + l];  // lane l = (point p, neighbor k)
  float4 own = pkb[nb0 + p];
  float4 nbr = pkb[idxv];
  float rx = own.x - nbr.x, ry = own.y - nbr.y, rz = own.z - nbr.z;
  float delta[64];
#pragma unroll
  for (int o = 0; o < 64; ++o)
    delta[o] = fmaxf(fmaf(Mrow[o * 3 + 2], rz, fmaf(Mrow[o * 3 + 1], ry, Mrow[o * 3] * rx)), 0.f);
  {  // pp = Gphi(own) - Gpsi(neighbor) staged to LDS (lane-row, stride 66)
    const float* phir = feat3T + (size_t)(Pb + p) * 192;
    const float* psir = feat3T + ((size_t)b * NPT + idxv) * 192 + 64;
#pragma unroll
    for (int o4 = 0; o4 < 16; ++o4) {
      float4 ph = *(const float4*)(phir + o4 * 4);
      float4 ps = *(const float4*)(psir + o4 * 4);
      int ad = l * SST + o4 * 4;
      S[ad] = ph.x - ps.x;
      S[ad + 1] = ph.y - ps.y;
      S[ad + 2] = ph.z - ps.z;
      S[ad + 3] = ph.w - ps.w;
    }
  }
  // g = relu(pp + G.delta): uniform G rows via s_load, two acc chains
  for (int o = 0; o < 64; o += 2) {
    const float* g0 = G + o * 64;
    float a0 = 0.f, a1 = 0.f;
#pragma unroll
    for (int c = 0; c < 64; ++c) {
      a0 = fmaf(g0[c], delta[c], a0);
      a1 = fmaf(g0[64 + c], delta[c], a1);
    }
    int ad = l * SST + o;
    float pp0 = S[ad], pp1 = S[ad + 1];
    S[ad] = fmaxf(pp0 + a0, 0.f);
    S[ad + 1] = fmaxf(pp1 + a1, 0.f);
  }
  __syncthreads();  // ordering for cross-lane LDS reads below
  // read side: lane l = channel, loop over the wave's 4 points
  float m0v = McT[l], m1v = McT[64 + l], m2v = McT[128 + l];
#pragma unroll 1
  for (int j = 0; j < 4; ++j) {
    int nj = nb0 + j;
    float4 ownq = pkb[nj];
    float gv[16], dl[16];
    int sidx[16];
    float mx = -1e30f;
#pragma unroll
    for (int r = 0; r < 16; ++r) {
      int si = __builtin_amdgcn_readlane(idxv, j * 16 + r);
      sidx[r] = si;
      float4 nbq = pkb[si];
      float rxq = ownq.x - nbq.x, ryq = ownq.y - nbq.y, rzq = ownq.z - nbq.z;
      dl[r] = fmaxf(fmaf(m2v, rzq, fmaf(m1v, ryq, m0v * rxq)), 0.f);
      gv[r] = S[(j * 16 + r) * SST + l];
      mx = fmaxf(mx, gv[r]);
    }
    float s = 0.f;
#pragma unroll
    for (int r = 0; r < 16; ++r) {
      float e = expf(gv[r] - mx);
      gv[r] = e;
      s += e;
    }
    float inv = 1.0f / s;
    float acc = 0.f;
#pragma unroll
    for (int r = 0; r < 16; ++r) {
      float al = feat3T[((size_t)b * NPT + sidx[r]) * 192 + 128 + l];
      acc = fmaf(gv[r] * inv, al + dl[r], acc);
    }
    out[(size_t)b * 64 * NPT + (size_t)l * NPT + nj] = acc;
  }
}

extern "C" void kernel_launch(void* const* d_in, const int* in_sizes, int n_in,
                              void* d_out, int out_size, void* d_ws, size_t ws_size,
                              hipStream_t stream) {
  const float* features = (const float*)d_in[0];
  const float* coords = (const float*)d_in[1];
  const float* w_lin = (const float*)d_in[2];
  const float* w_t1 = (const float*)d_in[3];
  const float* w_t2 = (const float*)d_in[4];
  const float* w_g1 = (const float*)d_in[5];
  const float* w_g2 = (const float*)d_in[6];
  float* out = (float*)d_out;
  char* ws = (char*)d_ws;
  // workspace layout (~26.9 MB total; part overlaps feat3T, consumed first)
  float4* pack = (float4*)ws;                   // 524288 B
  float* G = (float*)(ws + 524288);             // 16384 B
  float* Mrow = (float*)(ws + 540672);          // 768 B
  float* McT = (float*)(ws + 541440);           // 768 B
  float* wcomb = (float*)(ws + 542208);         // 49152 B
  int* idxk = (int*)(ws + 591360);              // 2 MB
  float* feat3T = (float*)(ws + 2688512);       // 24 MB
  u32* part = (u32*)(ws + 2688512);             // 12.6 MB (overlap, freed by refine)

  fold1_k<<<17, 256, 0, stream>>>(w_g1, w_g2, w_t1, w_t2, G, Mrow, McT);
  fold2_k<<<48, 256, 0, stream>>>(G, w_lin, wcomb);
  pack_k<<<128, 256, 0, stream>>>(coords, pack);
  knn_k<<<dim3(128, 4, NSEG), 64, 0, stream>>>(pack, part);
  refine_k<<<128, 256, 0, stream>>>(pack, part, idxk);
  feat_k<<<256, 256, 0, stream>>>(features, wcomb, feat3T);  // after refine: reuses part region
  attn_k<<<4096, 128, 0, stream>>>(pack, idxk, feat3T, G, Mrow, McT, out);
}

// Round 5
// 707.431 us; speedup vs baseline: 1.3736x; 1.3539x over previous
//
#include <hip/hip_runtime.h>
#include <cstdint>

// PointTransformerLayer, MI355X. Folded-weight formulation:
//   M  = Wt2@Wt1 (64x3)          delta = relu(M . rel)
//   G  = Wg2@Wg1 (64x64)         g = relu(Gphi[n] - Gpsi[idx] + G.delta)
//   GW1= G@Wlin[0:64], GW2 = G@Wlin[64:128], alpha = Wlin[128:192] @ f
// KNN: fp32 prefilter (scalar-loaded candidates, u32 packed keys
//      d2hi|idx, top-20 per 1024-segment), then NUMPY-FP32-BIT-EXACT
//      re-rank of the 160 survivors (no-FMA sequential fp32 d2, ties by
//      lowest index = stable top_k).
// R4 evidence: knn 531us @ VALUBusy 58% / Occ 15% / conflicts 0 ->
// instruction-fat + latency-exposed. R5: s_load candidates (SMEM pipe),
// u32 keys (3-instr insertion slots), NSEG=8 (4096 waves). attn: 64x32
// channel-split LDS strip (8.4KB), 64-thr blocks, __expf. absmax floor
// is bf16 ulp (harness compares at bf16), so fast-math headroom is ~6x.

#define NPT 8192
typedef unsigned long long u64;
typedef unsigned int u32;

// ---------- fold1: G = Wg2@Wg1 (64x64); M = Wt2@Wt1 (64x3, row + colT) ----
__global__ __launch_bounds__(256) void fold1_k(
    const float* __restrict__ wg1, const float* __restrict__ wg2,
    const float* __restrict__ wt1, const float* __restrict__ wt2,
    float* __restrict__ G, float* __restrict__ Mrow, float* __restrict__ McT) {
  int t = blockIdx.x * 256 + threadIdx.x;
  if (t < 4096) {
    int o = t >> 6, c = t & 63;
    float acc = 0.f;
    for (int cp = 0; cp < 64; ++cp) acc = fmaf(wg2[o * 64 + cp], wg1[cp * 64 + c], acc);
    G[o * 64 + c] = acc;
  } else if (t < 4096 + 192) {
    int i = t - 4096;
    int o = i / 3, j = i - o * 3;
    float acc = 0.f;
    for (int c = 0; c < 64; ++c) acc = fmaf(wt2[o * 64 + c], wt1[c * 3 + j], acc);
    Mrow[o * 3 + j] = acc;
    McT[j * 64 + o] = acc;
  }
}

// ---------- fold2: wcomb rows [0:64)=G@W1, [64:128)=G@W2, [128:192)=Wlin ---
__global__ __launch_bounds__(256) void fold2_k(
    const float* __restrict__ G, const float* __restrict__ wl,
    float* __restrict__ wcomb) {
  int t = blockIdx.x * 256 + threadIdx.x;  // 12288
  int o = t >> 6, c = t & 63;
  float acc = 0.f;
  if (o < 64) {
    for (int cp = 0; cp < 64; ++cp) acc = fmaf(G[o * 64 + cp], wl[cp * 64 + c], acc);
  } else if (o < 128) {
    for (int cp = 0; cp < 64; ++cp) acc = fmaf(G[(o - 64) * 64 + cp], wl[(64 + cp) * 64 + c], acc);
  } else {
    acc = wl[o * 64 + c];
  }
  wcomb[o * 64 + c] = acc;
}

// ---------- pack coords as float4 (x,y,z,sq) with NP-EXACT sq -------------
// sq matches np.sum(coords*coords, axis=1): ((x*x + y*y) + z*z), no FMA.
__global__ __launch_bounds__(256) void pack_k(const float* __restrict__ coords,
                                              float4* __restrict__ pack) {
  int g = blockIdx.x * 256 + threadIdx.x;  // 32768
  int b = g >> 13, n = g & (NPT - 1);
  const float* c = coords + (size_t)b * 3 * NPT;
  float x = c[n], y = c[NPT + n], z = c[2 * NPT + n];
  float sq = __fadd_rn(__fadd_rn(__fmul_rn(x, x), __fmul_rn(y, y)), __fmul_rn(z, z));
  pack[g] = make_float4(x, y, z, sq);
}

// ---------- KNN prefilter: top-20 per 1024-candidate segment --------------
// u32 key = (d2bits & ~0x1FFF) | idx  (idx < 8192 = 13 bits). Key blur
// ~1e-3 relative; 4 spare slots need >=5 simultaneous sub-0.1%-gap
// inversions to break np-fp32-top-16 recall: never. Candidates are
// wave-uniform -> scalar loads (SMEM pipe, no VALU broadcast).
#define MKEEP 20
#define SEGSZ 1024
#define NSEG 8
#define CAP 28
#define DRAIN_AT 12
__global__ __launch_bounds__(64) void knn_k(const float4* __restrict__ pack,
                                            u32* __restrict__ part) {
  __shared__ u32 buf[CAP * 64];  // [slot][lane]: conflict-free
  int tid = threadIdx.x;         // == lane (wave-synchronous block)
  int b = blockIdx.y, seg = blockIdx.z;
  int n = blockIdx.x * 64 + tid;
  const float4* pk = pack + (size_t)b * NPT;
  float4 q = pk[n];
  float qsq = q.w;
  u32 arr[MKEEP];
#pragma unroll
  for (int j = 0; j < MKEEP; ++j) arr[j] = 0xFFFFFFFFu;
  u32 Tkey = 0xFFFFFFFFu;
  int cnt = 0;
  int m0 = seg * SEGSZ;
  for (int mc = m0; mc < m0 + SEGSZ; mc += 16) {
    const float4* cp = pk + mc;  // uniform address -> s_load_dwordx4 batch
#pragma unroll
    for (int j = 0; j < 16; ++j) {
      float4 c4 = cp[j];
      float dot = fmaf(q.z, c4.z, fmaf(q.y, c4.y, q.x * c4.x));
      float d2 = fmaf(-2.f, dot, qsq + c4.w);
      d2 = fmaxf(d2, 0.f);  // monotone u32 order (self ~0)
      u32 key = (__float_as_uint(d2) & 0xFFFFE000u) | (u32)(mc + j);
      if (key <= Tkey) {  // conservative guard vs current 20th-best
        buf[cnt * 64 + tid] = key;
        ++cnt;
      }
    }
    if (__ballot(cnt >= DRAIN_AT)) {  // wave-parallel amortized maintenance
      for (int t2 = 0;; ++t2) {
        if (!__ballot(t2 < cnt)) break;
        if (t2 < cnt) {
          u32 key = buf[t2 * 64 + tid];
          if (key < arr[MKEEP - 1]) {
#pragma unroll
            for (int qq = 0; qq < MKEEP; ++qq) {
              bool cs = key < arr[qq];
              u32 tmp = arr[qq];
              arr[qq] = cs ? key : tmp;
              key = cs ? tmp : key;
            }
          }
        }
      }
      cnt = 0;
      Tkey = arr[MKEEP - 1];
    }
  }
  for (int t2 = 0;; ++t2) {  // final drain
    if (!__ballot(t2 < cnt)) break;
    if (t2 < cnt) {
      u32 key = buf[t2 * 64 + tid];
      if (key < arr[MKEEP - 1]) {
#pragma unroll
        for (int qq = 0; qq < MKEEP; ++qq) {
          bool cs = key < arr[qq];
          u32 tmp = arr[qq];
          arr[qq] = cs ? key : tmp;
          key = cs ? tmp : key;
        }
      }
    }
  }
  size_t g = (size_t)b * NPT + n;
#pragma unroll
  for (int j = 0; j < MKEEP; ++j)
    part[g * (NSEG * MKEEP) + (size_t)seg * MKEEP + j] = arr[j] & 0x1FFFu;
}

// ---------- numpy-fp32-bit-exact re-rank of the 160 survivors -------------
// d2 = fl(fl(sq_n+sq_m) - fl(2*dot)), dot sequential no-FMA. Negative d2
// legal; float compares; ties by lowest index == stable top_k.
__global__ __launch_bounds__(256) void refine_k(const float4* __restrict__ pack,
                                                const u32* __restrict__ part,
                                                int* __restrict__ idxk) {
  int g = blockIdx.x * 256 + threadIdx.x;  // 32768
  int b = g >> 13;
  const float4* pk = pack + (size_t)b * NPT;
  float4 q = pk[g & (NPT - 1)];
  float qx = q.x, qy = q.y, qz = q.z, qs = q.w;
  float bd[16];
  int bi[16];
#pragma unroll
  for (int j = 0; j < 16; ++j) { bd[j] = 1e30f; bi[j] = 0x7FFFFFFF; }
  const u32* p = part + (size_t)g * (NSEG * MKEEP);
  for (int j = 0; j < NSEG * MKEEP; ++j) {
    int m = (int)p[j];
    float4 pm = pk[m];
    float dot = __fadd_rn(__fadd_rn(__fmul_rn(qx, pm.x), __fmul_rn(qy, pm.y)),
                          __fmul_rn(qz, pm.z));
    float kd = __fsub_rn(__fadd_rn(qs, pm.w), __fmul_rn(2.0f, dot));
    int ki = m;
    if (kd < bd[15] || (kd == bd[15] && ki < bi[15])) {  // guarded chain
#pragma unroll
      for (int qq = 0; qq < 16; ++qq) {
        bool cs = (kd < bd[qq]) || (kd == bd[qq] && ki < bi[qq]);
        float td = bd[qq];
        int ti = bi[qq];
        bd[qq] = cs ? kd : td;
        bi[qq] = cs ? ki : ti;
        kd = cs ? td : kd;
        ki = cs ? ti : ki;
      }
    }
  }
#pragma unroll
  for (int j = 0; j < 16; ++j) idxk[(size_t)g * 16 + j] = bi[j];
}

// ---------- feat: feat3T[P][0:64)=Gphi, [64:128)=Gpsi, [128:192)=alpha ----
__global__ __launch_bounds__(256) void feat_k(const float* __restrict__ features,
                                              const float* __restrict__ wcomb,
                                              float* __restrict__ feat3T) {
  int t = blockIdx.x * 256 + threadIdx.x;  // 65536
  int half = t >> 15;
  int P = t & 32767;
  int b = P >> 13, n = P & (NPT - 1);
  const float* fin = features + (size_t)b * 64 * NPT + n;
  float f[64];
#pragma unroll
  for (int c = 0; c < 64; ++c) f[c] = fin[(size_t)c * NPT];
  const float* W = wcomb + half * 96 * 64;
  float* op = feat3T + (size_t)P * 192 + half * 96;
  for (int r4 = 0; r4 < 24; ++r4) {
    float a0 = 0.f, a1 = 0.f, a2 = 0.f, a3 = 0.f;
    const float* w0 = W + (r4 * 4) * 64;
#pragma unroll
    for (int c = 0; c < 64; ++c) {
      a0 = fmaf(w0[c], f[c], a0);
      a1 = fmaf(w0[64 + c], f[c], a1);
      a2 = fmaf(w0[128 + c], f[c], a2);
      a3 = fmaf(w0[192 + c], f[c], a3);
    }
    *(float4*)(op + r4 * 4) = make_float4(a0, a1, a2, a3);
  }
}

// ---------- attention: 1 wave = 4 points; channel-split 64x32 LDS strip ---
// Two passes over channel halves: write g for 32 channels (all 64 pairs),
// then read transposed (lane = (j2, c2)): softmax over k + weighted sum.
// LDS 8.4KB/wave -> ~2x occupancy vs 64x64 strip.
#define SST2 33
__global__ __launch_bounds__(64, 3) void attn_k(
    const float4* __restrict__ pack, const int* __restrict__ idxk,
    const float* __restrict__ feat3T, const float* __restrict__ G,
    const float* __restrict__ Mrow, const float* __restrict__ McT,
    float* __restrict__ out) {
  __shared__ float S[64 * SST2];
  int l = threadIdx.x;
  int Pb = blockIdx.x * 4;
  int b = Pb >> 13;
  int nb0 = Pb & (NPT - 1);
  int p = l >> 4;
  const float4* pkb = pack + (size_t)b * NPT;
  int idxv = idxk[(size_t)Pb * 16 + l];  // lane l = (point p, neighbor k)
  float4 own = pkb[nb0 + p];
  float4 nbr = pkb[idxv];
  float rx = own.x - nbr.x, ry = own.y - nbr.y, rz = own.z - nbr.z;
  float delta[64];
#pragma unroll
  for (int o = 0; o < 64; ++o)
    delta[o] = fmaxf(fmaf(Mrow[o * 3 + 2], rz, fmaf(Mrow[o * 3 + 1], ry, Mrow[o * 3] * rx)), 0.f);
  int c2 = l & 31, j2 = l >> 5;
  const float* phir = feat3T + (size_t)(Pb + p) * 192;
  const float* psir = feat3T + ((size_t)b * NPT + idxv) * 192 + 64;
#pragma unroll 1
  for (int pass = 0; pass < 2; ++pass) {
    // ---- write phase: channels [32*pass, 32*pass+32), row = pair lane ----
#pragma unroll
    for (int o4 = 0; o4 < 8; ++o4) {
      float4 ph = *(const float4*)(phir + pass * 32 + o4 * 4);
      float4 ps = *(const float4*)(psir + pass * 32 + o4 * 4);
      const float* gr = G + (pass * 32 + o4 * 4) * 64;
      float g0 = 0.f, g1 = 0.f, g2 = 0.f, g3 = 0.f;
#pragma unroll
      for (int c = 0; c < 64; ++c) {
        g0 = fmaf(gr[c], delta[c], g0);
        g1 = fmaf(gr[64 + c], delta[c], g1);
        g2 = fmaf(gr[128 + c], delta[c], g2);
        g3 = fmaf(gr[192 + c], delta[c], g3);
      }
      int ad = l * SST2 + o4 * 4;
      S[ad] = fmaxf(ph.x - ps.x + g0, 0.f);
      S[ad + 1] = fmaxf(ph.y - ps.y + g1, 0.f);
      S[ad + 2] = fmaxf(ph.z - ps.z + g2, 0.f);
      S[ad + 3] = fmaxf(ph.w - ps.w + g3, 0.f);
    }
    __syncthreads();
    // ---- read phase: lane = (j2, c2); 2 points per iteration -------------
    float m0v = McT[pass * 32 + c2];
    float m1v = McT[64 + pass * 32 + c2];
    float m2v = McT[128 + pass * 32 + c2];
#pragma unroll 1
    for (int jj = 0; jj < 2; ++jj) {
      int pj = jj * 2 + j2;
      int nj = nb0 + pj;
      float4 ownq = pkb[nj];
      float gvv[16];
      float mx = -1e30f;
#pragma unroll
      for (int r = 0; r < 16; ++r) {
        gvv[r] = S[(pj * 16 + r) * SST2 + c2];
        mx = fmaxf(mx, gvv[r]);
      }
      float s = 0.f;
#pragma unroll
      for (int r = 0; r < 16; ++r) {
        float e = __expf(gvv[r] - mx);
        gvv[r] = e;
        s += e;
      }
      float inv = 1.0f / s;
      float acc = 0.f;
#pragma unroll
      for (int r = 0; r < 16; ++r) {
        int si = __shfl(idxv, pj * 16 + r);
        float4 nbq = pkb[si];
        float dl = fmaxf(fmaf(m2v, ownq.z - nbq.z,
                              fmaf(m1v, ownq.y - nbq.y, m0v * (ownq.x - nbq.x))), 0.f);
        float al = feat3T[((size_t)b * NPT + si) * 192 + 128 + pass * 32 + c2];
        acc = fmaf(gvv[r] * inv, al + dl, acc);
      }
      out[(size_t)b * 64 * NPT + (size_t)(pass * 32 + c2) * NPT + nj] = acc;
    }
    __syncthreads();  // strip reused by next pass
  }
}

extern "C" void kernel_launch(void* const* d_in, const int* in_sizes, int n_in,
                              void* d_out, int out_size, void* d_ws, size_t ws_size,
                              hipStream_t stream) {
  const float* features = (const float*)d_in[0];
  const float* coords = (const float*)d_in[1];
  const float* w_lin = (const float*)d_in[2];
  const float* w_t1 = (const float*)d_in[3];
  const float* w_t2 = (const float*)d_in[4];
  const float* w_g1 = (const float*)d_in[5];
  const float* w_g2 = (const float*)d_in[6];
  float* out = (float*)d_out;
  char* ws = (char*)d_ws;
  // workspace layout (~26.9 MB total; part overlaps feat3T, consumed first)
  float4* pack = (float4*)ws;                   // 524288 B
  float* G = (float*)(ws + 524288);             // 16384 B
  float* Mrow = (float*)(ws + 540672);          // 768 B
  float* McT = (float*)(ws + 541440);           // 768 B
  float* wcomb = (float*)(ws + 542208);         // 49152 B
  int* idxk = (int*)(ws + 591360);              // 2 MB
  float* feat3T = (float*)(ws + 2688512);       // 24 MB
  u32* part = (u32*)(ws + 2688512);             // 21 MB (overlap, freed by refine)

  fold1_k<<<17, 256, 0, stream>>>(w_g1, w_g2, w_t1, w_t2, G, Mrow, McT);
  fold2_k<<<48, 256, 0, stream>>>(G, w_lin, wcomb);
  pack_k<<<128, 256, 0, stream>>>(coords, pack);
  knn_k<<<dim3(128, 4, NSEG), 64, 0, stream>>>(pack, part);
  refine_k<<<128, 256, 0, stream>>>(pack, part, idxk);
  feat_k<<<256, 256, 0, stream>>>(features, wcomb, feat3T);  // after refine: reuses part region
  attn_k<<<8192, 64, 0, stream>>>(pack, idxk, feat3T, G, Mrow, McT, out);
}

// Round 6
// 672.149 us; speedup vs baseline: 1.4458x; 1.0525x over previous
//
#include <hip/hip_runtime.h>
#include <cstdint>

// PointTransformerLayer, MI355X. Folded-weight formulation:
//   M  = Wt2@Wt1 (64x3)          delta = relu(M . rel)
//   G  = Wg2@Wg1 (64x64)         g = relu(Gphi[n] - Gpsi[idx] + G.delta)
//   GW1= G@Wlin[0:64], GW2 = G@Wlin[64:128], alpha = Wlin[128:192] @ f
// KNN: fp32 prefilter (uniform scalar candidate loads, u32 packed keys
//      d2hi|idx, top-20 per 1024-segment, min/max bubble chains), part
//      stored TRANSPOSED [slot][point] (coalesced), then global top-24 by
//      blurred key, then NUMPY-FP32-BIT-EXACT re-rank of those 24 (no-FMA
//      sequential fp32 d2, ties by lowest index = stable top_k).
// R5 evidence: knn 284us @ VALUBusy 80% -> ~66 VALU/cand, dominated by
// insertion-chain issue (3 instr/slot) + append block; part 640B-strided.
// R6: min/max chain (2/slot), coalesced part, refine 160->24 random loads,
// attn launch_bounds(64) (un-cap VGPR; suspected scratch spill at (64,3)).

#define NPT 8192
typedef unsigned long long u64;
typedef unsigned int u32;

// ---------- fold1: G = Wg2@Wg1 (64x64); M = Wt2@Wt1 (64x3, row + colT) ----
__global__ __launch_bounds__(256) void fold1_k(
    const float* __restrict__ wg1, const float* __restrict__ wg2,
    const float* __restrict__ wt1, const float* __restrict__ wt2,
    float* __restrict__ G, float* __restrict__ Mrow, float* __restrict__ McT) {
  int t = blockIdx.x * 256 + threadIdx.x;
  if (t < 4096) {
    int o = t >> 6, c = t & 63;
    float acc = 0.f;
    for (int cp = 0; cp < 64; ++cp) acc = fmaf(wg2[o * 64 + cp], wg1[cp * 64 + c], acc);
    G[o * 64 + c] = acc;
  } else if (t < 4096 + 192) {
    int i = t - 4096;
    int o = i / 3, j = i - o * 3;
    float acc = 0.f;
    for (int c = 0; c < 64; ++c) acc = fmaf(wt2[o * 64 + c], wt1[c * 3 + j], acc);
    Mrow[o * 3 + j] = acc;
    McT[j * 64 + o] = acc;
  }
}

// ---------- fold2: wcomb rows [0:64)=G@W1, [64:128)=G@W2, [128:192)=Wlin ---
__global__ __launch_bounds__(256) void fold2_k(
    const float* __restrict__ G, const float* __restrict__ wl,
    float* __restrict__ wcomb) {
  int t = blockIdx.x * 256 + threadIdx.x;  // 12288
  int o = t >> 6, c = t & 63;
  float acc = 0.f;
  if (o < 64) {
    for (int cp = 0; cp < 64; ++cp) acc = fmaf(G[o * 64 + cp], wl[cp * 64 + c], acc);
  } else if (o < 128) {
    for (int cp = 0; cp < 64; ++cp) acc = fmaf(G[(o - 64) * 64 + cp], wl[(64 + cp) * 64 + c], acc);
  } else {
    acc = wl[o * 64 + c];
  }
  wcomb[o * 64 + c] = acc;
}

// ---------- pack coords as float4 (x,y,z,sq) with NP-EXACT sq -------------
// sq matches np.sum(coords*coords, axis=1): ((x*x + y*y) + z*z), no FMA.
__global__ __launch_bounds__(256) void pack_k(const float* __restrict__ coords,
                                              float4* __restrict__ pack) {
  int g = blockIdx.x * 256 + threadIdx.x;  // 32768
  int b = g >> 13, n = g & (NPT - 1);
  const float* c = coords + (size_t)b * 3 * NPT;
  float x = c[n], y = c[NPT + n], z = c[2 * NPT + n];
  float sq = __fadd_rn(__fadd_rn(__fmul_rn(x, x), __fmul_rn(y, y)), __fmul_rn(z, z));
  pack[g] = make_float4(x, y, z, sq);
}

// ---------- KNN prefilter: top-20 per 1024-candidate segment --------------
// u32 key = (d2bits & ~0x1FFF) | idx  (idx < 8192 = 13 bits). Blur ~0.1%
// relative << rank gaps; 4 spare slots per segment guarantee local-top-16
// recall. Candidates wave-uniform -> scalar loads. Insertion = min/max
// bubble chain (2 VALU/slot).
#define MKEEP 20
#define SEGSZ 1024
#define NSEG 8
#define CAP 28
#define DRAIN_AT 12
#define NG (4 * NPT)
__global__ __launch_bounds__(64) void knn_k(const float4* __restrict__ pack,
                                            u32* __restrict__ part) {
  __shared__ u32 buf[CAP * 64];  // [slot][lane]: conflict-free
  int tid = threadIdx.x;         // == lane (wave-synchronous block)
  int b = blockIdx.y, seg = blockIdx.z;
  int n = blockIdx.x * 64 + tid;
  const float4* pk = pack + (size_t)b * NPT;
  float4 q = pk[n];
  float qsq = q.w;
  u32 arr[MKEEP];
#pragma unroll
  for (int j = 0; j < MKEEP; ++j) arr[j] = 0xFFFFFFFFu;
  u32 Tkey = 0xFFFFFFFFu;
  int cnt = 0;
  int m0 = seg * SEGSZ;
  for (int mc = m0; mc < m0 + SEGSZ; mc += 16) {
    const float4* cp = pk + mc;  // uniform address -> scalar-load batch
#pragma unroll
    for (int j = 0; j < 16; ++j) {
      float4 c4 = cp[j];
      float dot = fmaf(q.z, c4.z, fmaf(q.y, c4.y, q.x * c4.x));
      float d2 = fmaf(-2.f, dot, qsq + c4.w);
      d2 = fmaxf(d2, 0.f);  // monotone u32 order (self ~0; FMA can go <0)
      u32 key = (__float_as_uint(d2) & 0xFFFFE000u) | (u32)(mc + j);
      if (key <= Tkey) {  // conservative guard vs current 20th-best
        buf[cnt * 64 + tid] = key;
        ++cnt;
      }
    }
    if (__ballot(cnt >= DRAIN_AT)) {  // wave-parallel amortized maintenance
      for (int t2 = 0;; ++t2) {
        if (!__ballot(t2 < cnt)) break;
        if (t2 < cnt) {
          u32 key = buf[t2 * 64 + tid];
          if (key < arr[MKEEP - 1]) {
#pragma unroll
            for (int qq = 0; qq < MKEEP; ++qq) {  // min/max bubble: 2 instr/slot
              u32 t = arr[qq];
              arr[qq] = min(t, key);
              key = max(t, key);
            }
          }
        }
      }
      cnt = 0;
      Tkey = arr[MKEEP - 1];
    }
  }
  for (int t2 = 0;; ++t2) {  // final drain
    if (!__ballot(t2 < cnt)) break;
    if (t2 < cnt) {
      u32 key = buf[t2 * 64 + tid];
      if (key < arr[MKEEP - 1]) {
#pragma unroll
        for (int qq = 0; qq < MKEEP; ++qq) {
          u32 t = arr[qq];
          arr[qq] = min(t, key);
          key = max(t, key);
        }
      }
    }
  }
  // transposed store: row = (seg,slot), col = point -> coalesced
  size_t g = (size_t)b * NPT + n;
#pragma unroll
  for (int j = 0; j < MKEEP; ++j)
    part[(size_t)(seg * MKEEP + j) * NG + g] = arr[j];
}

// ---------- refine: global top-24 by blurred key, then np-exact top-16 ----
// Phase 1: coalesced scan of 160 keys -> 24 smallest (blur 0.1% << rank
// 16->24 d2 gap ~40%: recall certain). Phase 2: d2 = fl(fl(sq_n+sq_m) -
// fl(2*dot)), dot sequential no-FMA; ties by lowest index == stable top_k.
__global__ __launch_bounds__(256) void refine_k(const float4* __restrict__ pack,
                                                const u32* __restrict__ part,
                                                int* __restrict__ idxk) {
  int g = blockIdx.x * 256 + threadIdx.x;  // 32768
  int b = g >> 13;
  u32 ka[24];
#pragma unroll
  for (int j = 0; j < 24; ++j) ka[j] = 0xFFFFFFFFu;
  for (int s = 0; s < NSEG * MKEEP; ++s) {
    u32 key = part[(size_t)s * NG + g];  // coalesced
    if (key < ka[23]) {
#pragma unroll
      for (int qq = 0; qq < 24; ++qq) {
        u32 t = ka[qq];
        ka[qq] = min(t, key);
        key = max(t, key);
      }
    }
  }
  const float4* pk = pack + (size_t)b * NPT;
  float4 q = pk[g & (NPT - 1)];
  float qx = q.x, qy = q.y, qz = q.z, qs = q.w;
  float bd[16];
  int bi[16];
#pragma unroll
  for (int j = 0; j < 16; ++j) { bd[j] = 1e30f; bi[j] = 0x7FFFFFFF; }
#pragma unroll 1
  for (int j = 0; j < 24; ++j) {
    int m = (int)(ka[j] & 0x1FFFu);
    float4 pm = pk[m];
    float dot = __fadd_rn(__fadd_rn(__fmul_rn(qx, pm.x), __fmul_rn(qy, pm.y)),
                          __fmul_rn(qz, pm.z));
    float kd = __fsub_rn(__fadd_rn(qs, pm.w), __fmul_rn(2.0f, dot));
    int ki = m;
    if (kd < bd[15] || (kd == bd[15] && ki < bi[15])) {  // guarded chain
#pragma unroll
      for (int qq = 0; qq < 16; ++qq) {
        bool cs = (kd < bd[qq]) || (kd == bd[qq] && ki < bi[qq]);
        float td = bd[qq];
        int ti = bi[qq];
        bd[qq] = cs ? kd : td;
        bi[qq] = cs ? ki : ti;
        kd = cs ? td : kd;
        ki = cs ? ti : ki;
      }
    }
  }
#pragma unroll
  for (int j = 0; j < 16; ++j) idxk[(size_t)g * 16 + j] = bi[j];
}

// ---------- feat: feat3T[P][0:64)=Gphi, [64:128)=Gpsi, [128:192)=alpha ----
__global__ __launch_bounds__(256) void feat_k(const float* __restrict__ features,
                                              const float* __restrict__ wcomb,
                                              float* __restrict__ feat3T) {
  int t = blockIdx.x * 256 + threadIdx.x;  // 65536
  int half = t >> 15;
  int P = t & 32767;
  int b = P >> 13, n = P & (NPT - 1);
  const float* fin = features + (size_t)b * 64 * NPT + n;
  float f[64];
#pragma unroll
  for (int c = 0; c < 64; ++c) f[c] = fin[(size_t)c * NPT];
  const float* W = wcomb + half * 96 * 64;
  float* op = feat3T + (size_t)P * 192 + half * 96;
  for (int r4 = 0; r4 < 24; ++r4) {
    float a0 = 0.f, a1 = 0.f, a2 = 0.f, a3 = 0.f;
    const float* w0 = W + (r4 * 4) * 64;
#pragma unroll
    for (int c = 0; c < 64; ++c) {
      a0 = fmaf(w0[c], f[c], a0);
      a1 = fmaf(w0[64 + c], f[c], a1);
      a2 = fmaf(w0[128 + c], f[c], a2);
      a3 = fmaf(w0[192 + c], f[c], a3);
    }
    *(float4*)(op + r4 * 4) = make_float4(a0, a1, a2, a3);
  }
}

// ---------- attention: 1 wave = 4 points; channel-split 64x32 LDS strip ---
// Two passes over channel halves: write g for 32 channels (all 64 pairs),
// then read transposed (lane = (j2, c2)): softmax over k + weighted sum.
// launch_bounds(64) only: delta[64]+temps need VGPR headroom (no spill).
#define SST2 33
__global__ __launch_bounds__(64) void attn_k(
    const float4* __restrict__ pack, const int* __restrict__ idxk,
    const float* __restrict__ feat3T, const float* __restrict__ G,
    const float* __restrict__ Mrow, const float* __restrict__ McT,
    float* __restrict__ out) {
  __shared__ float S[64 * SST2];
  int l = threadIdx.x;
  int Pb = blockIdx.x * 4;
  int b = Pb >> 13;
  int nb0 = Pb & (NPT - 1);
  int p = l >> 4;
  const float4* pkb = pack + (size_t)b * NPT;
  int idxv = idxk[(size_t)Pb * 16 + l];  // lane l = (point p, neighbor k)
  float4 own = pkb[nb0 + p];
  float4 nbr = pkb[idxv];
  float rx = own.x - nbr.x, ry = own.y - nbr.y, rz = own.z - nbr.z;
  float delta[64];
#pragma unroll
  for (int o = 0; o < 64; ++o)
    delta[o] = fmaxf(fmaf(Mrow[o * 3 + 2], rz, fmaf(Mrow[o * 3 + 1], ry, Mrow[o * 3] * rx)), 0.f);
  int c2 = l & 31, j2 = l >> 5;
  const float* phir = feat3T + (size_t)(Pb + p) * 192;
  const float* psir = feat3T + ((size_t)b * NPT + idxv) * 192 + 64;
#pragma unroll 1
  for (int pass = 0; pass < 2; ++pass) {
    // ---- write phase: channels [32*pass, 32*pass+32), row = pair lane ----
#pragma unroll
    for (int o4 = 0; o4 < 8; ++o4) {
      float4 ph = *(const float4*)(phir + pass * 32 + o4 * 4);
      float4 ps = *(const float4*)(psir + pass * 32 + o4 * 4);
      const float* gr = G + (pass * 32 + o4 * 4) * 64;
      float g0 = 0.f, g1 = 0.f, g2 = 0.f, g3 = 0.f;
#pragma unroll
      for (int c = 0; c < 64; ++c) {
        g0 = fmaf(gr[c], delta[c], g0);
        g1 = fmaf(gr[64 + c], delta[c], g1);
        g2 = fmaf(gr[128 + c], delta[c], g2);
        g3 = fmaf(gr[192 + c], delta[c], g3);
      }
      int ad = l * SST2 + o4 * 4;
      S[ad] = fmaxf(ph.x - ps.x + g0, 0.f);
      S[ad + 1] = fmaxf(ph.y - ps.y + g1, 0.f);
      S[ad + 2] = fmaxf(ph.z - ps.z + g2, 0.f);
      S[ad + 3] = fmaxf(ph.w - ps.w + g3, 0.f);
    }
    __syncthreads();
    // ---- read phase: lane = (j2, c2); 2 points per iteration -------------
    float m0v = McT[pass * 32 + c2];
    float m1v = McT[64 + pass * 32 + c2];
    float m2v = McT[128 + pass * 32 + c2];
#pragma unroll 1
    for (int jj = 0; jj < 2; ++jj) {
      int pj = jj * 2 + j2;
      int nj = nb0 + pj;
      float4 ownq = pkb[nj];
      float gvv[16];
      float mx = -1e30f;
#pragma unroll
      for (int r = 0; r < 16; ++r) {
        gvv[r] = S[(pj * 16 + r) * SST2 + c2];
        mx = fmaxf(mx, gvv[r]);
      }
      float s = 0.f;
#pragma unroll
      for (int r = 0; r < 16; ++r) {
        float e = __expf(gvv[r] - mx);
        gvv[r] = e;
        s += e;
      }
      float inv = 1.0f / s;
      float acc = 0.f;
#pragma unroll
      for (int r = 0; r < 16; ++r) {
        int si = __shfl(idxv, pj * 16 + r);
        float4 nbq = pkb[si];
        float dl = fmaxf(fmaf(m2v, ownq.z - nbq.z,
                              fmaf(m1v, ownq.y - nbq.y, m0v * (ownq.x - nbq.x))), 0.f);
        float al = feat3T[((size_t)b * NPT + si) * 192 + 128 + pass * 32 + c2];
        acc = fmaf(gvv[r] * inv, al + dl, acc);
      }
      out[(size_t)b * 64 * NPT + (size_t)(pass * 32 + c2) * NPT + nj] = acc;
    }
    __syncthreads();  // strip reused by next pass
  }
}

extern "C" void kernel_launch(void* const* d_in, const int* in_sizes, int n_in,
                              void* d_out, int out_size, void* d_ws, size_t ws_size,
                              hipStream_t stream) {
  const float* features = (const float*)d_in[0];
  const float* coords = (const float*)d_in[1];
  const float* w_lin = (const float*)d_in[2];
  const float* w_t1 = (const float*)d_in[3];
  const float* w_t2 = (const float*)d_in[4];
  const float* w_g1 = (const float*)d_in[5];
  const float* w_g2 = (const float*)d_in[6];
  float* out = (float*)d_out;
  char* ws = (char*)d_ws;
  // workspace layout (~26.9 MB total; part overlaps feat3T, consumed first)
  float4* pack = (float4*)ws;                   // 524288 B
  float* G = (float*)(ws + 524288);             // 16384 B
  float* Mrow = (float*)(ws + 540672);          // 768 B
  float* McT = (float*)(ws + 541440);           // 768 B
  float* wcomb = (float*)(ws + 542208);         // 49152 B
  int* idxk = (int*)(ws + 591360);              // 2 MB
  float* feat3T = (float*)(ws + 2688512);       // 24 MB
  u32* part = (u32*)(ws + 2688512);             // 21 MB (overlap, freed by refine)

  fold1_k<<<17, 256, 0, stream>>>(w_g1, w_g2, w_t1, w_t2, G, Mrow, McT);
  fold2_k<<<48, 256, 0, stream>>>(G, w_lin, wcomb);
  pack_k<<<128, 256, 0, stream>>>(coords, pack);
  knn_k<<<dim3(128, 4, NSEG), 64, 0, stream>>>(pack, part);
  refine_k<<<128, 256, 0, stream>>>(pack, part, idxk);
  feat_k<<<256, 256, 0, stream>>>(features, wcomb, feat3T);  // after refine: reuses part region
  attn_k<<<8192, 64, 0, stream>>>(pack, idxk, feat3T, G, Mrow, McT, out);
}

// Round 7
// 545.711 us; speedup vs baseline: 1.7807x; 1.2317x over previous
//
#include <hip/hip_runtime.h>
#include <cstdint>

// PointTransformerLayer, MI355X. Folded-weight formulation:
//   M  = Wt2@Wt1 (64x3)          delta = relu(M . rel)
//   G  = Wg2@Wg1 (64x64)         g = relu(Gphi[n] - Gpsi[idx] + G.delta)
//   GW1= G@Wlin[0:64], GW2 = G@Wlin[64:128], alpha = Wlin[128:192] @ f
// KNN v3 (R7): lane-parallel. One wave = one query; lane scans stride-64
//   candidates from a block-shared LDS stage (8 queries/block => 8x reuse),
//   maintaining per-lane top-8 blurred keys IN REGISTERS (no LDS queue, no
//   drain loop, no wave-OR serialization -- R5/R6 evidence: broadcast-
//   scheme maintenance cost ~67 instr/cand, structural). Wave merge via
//   24-round shfl-butterfly -> global top-24 blurred keys -> refine does
//   NUMPY-FP32-BIT-EXACT re-rank of those 24 (no-FMA sequential fp32 d2,
//   ties by lowest index = stable top_k). Coverage: P(lane holds >=9 of
//   blurred-top-18) ~ 1.7e-10/query; 24-vs-16 margin >> key blur+FMA skew.

#define NPT 8192
typedef unsigned long long u64;
typedef unsigned int u32;

// ---------- fold1: G = Wg2@Wg1 (64x64); M = Wt2@Wt1 (64x3, row + colT) ----
__global__ __launch_bounds__(256) void fold1_k(
    const float* __restrict__ wg1, const float* __restrict__ wg2,
    const float* __restrict__ wt1, const float* __restrict__ wt2,
    float* __restrict__ G, float* __restrict__ Mrow, float* __restrict__ McT) {
  int t = blockIdx.x * 256 + threadIdx.x;
  if (t < 4096) {
    int o = t >> 6, c = t & 63;
    float acc = 0.f;
    for (int cp = 0; cp < 64; ++cp) acc = fmaf(wg2[o * 64 + cp], wg1[cp * 64 + c], acc);
    G[o * 64 + c] = acc;
  } else if (t < 4096 + 192) {
    int i = t - 4096;
    int o = i / 3, j = i - o * 3;
    float acc = 0.f;
    for (int c = 0; c < 64; ++c) acc = fmaf(wt2[o * 64 + c], wt1[c * 3 + j], acc);
    Mrow[o * 3 + j] = acc;
    McT[j * 64 + o] = acc;
  }
}

// ---------- fold2: wcomb rows [0:64)=G@W1, [64:128)=G@W2, [128:192)=Wlin ---
__global__ __launch_bounds__(256) void fold2_k(
    const float* __restrict__ G, const float* __restrict__ wl,
    float* __restrict__ wcomb) {
  int t = blockIdx.x * 256 + threadIdx.x;  // 12288
  int o = t >> 6, c = t & 63;
  float acc = 0.f;
  if (o < 64) {
    for (int cp = 0; cp < 64; ++cp) acc = fmaf(G[o * 64 + cp], wl[cp * 64 + c], acc);
  } else if (o < 128) {
    for (int cp = 0; cp < 64; ++cp) acc = fmaf(G[(o - 64) * 64 + cp], wl[(64 + cp) * 64 + c], acc);
  } else {
    acc = wl[o * 64 + c];
  }
  wcomb[o * 64 + c] = acc;
}

// ---------- pack coords as float4 (x,y,z,sq) with NP-EXACT sq -------------
// sq matches np.sum(coords*coords, axis=1): ((x*x + y*y) + z*z), no FMA.
__global__ __launch_bounds__(256) void pack_k(const float* __restrict__ coords,
                                              float4* __restrict__ pack) {
  int g = blockIdx.x * 256 + threadIdx.x;  // 32768
  int b = g >> 13, n = g & (NPT - 1);
  const float* c = coords + (size_t)b * 3 * NPT;
  float x = c[n], y = c[NPT + n], z = c[2 * NPT + n];
  float sq = __fadd_rn(__fadd_rn(__fmul_rn(x, x), __fmul_rn(y, y)), __fmul_rn(z, z));
  pack[g] = make_float4(x, y, z, sq);
}

// ---------- KNN v3: wave=query, per-lane reg top-8, wave merge top-24 -----
#define QPB 8       // queries (waves) per 512-thread block
#define CHUNK 1024  // candidates staged per round (16 KB LDS)
#define NQ 32768
__global__ __launch_bounds__(512) void knn_k(const float4* __restrict__ pack,
                                             u32* __restrict__ part) {
  __shared__ float4 C[CHUNK];
  int tid = threadIdx.x;
  int w = tid >> 6, lane = tid & 63;
  int query = blockIdx.x * QPB + w;  // 4096 blocks
  int b = query >> 13, n = query & (NPT - 1);
  const float4* pk = pack + (size_t)b * NPT;
  float4 q = pk[n];
  float qsq = q.w;
  u32 arr[8];
#pragma unroll
  for (int j = 0; j < 8; ++j) arr[j] = 0xFFFFFFFFu;
  for (int c0 = 0; c0 < NPT; c0 += CHUNK) {
    C[tid] = pk[c0 + tid];              // block-wide stage: 8x reuse
    C[tid + 512] = pk[c0 + tid + 512];
    __syncthreads();
#pragma unroll 4
    for (int t = 0; t < CHUNK / 64; ++t) {
      float4 c4 = C[t * 64 + lane];
      float dot = fmaf(q.z, c4.z, fmaf(q.y, c4.y, q.x * c4.x));
      float d2 = fmaxf(fmaf(-2.f, dot, qsq + c4.w), 0.f);
      u32 key = (__float_as_uint(d2) & 0xFFFFE000u) | (u32)(c0 + t * 64 + lane);
      if (key < arr[7]) {  // per-lane register chain, no wave serialization
#pragma unroll
        for (int qq = 0; qq < 8; ++qq) {
          u32 tt = arr[qq];
          arr[qq] = min(tt, key);
          key = max(tt, key);
        }
      }
    }
    __syncthreads();
  }
  // wave merge: 64 sorted 8-lists -> global top-24 (keys unique via idx bits)
  u32 head = arr[0];
  u32 mg = 0xFFFFFFFFu;
#pragma unroll 1
  for (int r = 0; r < 24; ++r) {
    u32 m = head;
#pragma unroll
    for (int s = 1; s < 64; s <<= 1) m = min(m, (u32)__shfl_xor((int)m, s));
    if (lane == r) mg = m;
    if (head == m) {  // unique owner pops its head
      arr[0] = arr[1]; arr[1] = arr[2]; arr[2] = arr[3]; arr[3] = arr[4];
      arr[4] = arr[5]; arr[5] = arr[6]; arr[6] = arr[7]; arr[7] = 0xFFFFFFFFu;
      head = arr[0];
    }
  }
  if (lane < 24) part[(size_t)lane * NQ + query] = mg;  // [slot][query]
}

// ---------- numpy-fp32-bit-exact re-rank of the 24 survivors --------------
// d2 = fl(fl(sq_n+sq_m) - fl(2*dot)), dot sequential no-FMA. Negative d2
// legal; float compares; ties by lowest index == stable top_k.
__global__ __launch_bounds__(256) void refine_k(const float4* __restrict__ pack,
                                                const u32* __restrict__ part,
                                                int* __restrict__ idxk) {
  int g = blockIdx.x * 256 + threadIdx.x;  // 32768
  int b = g >> 13;
  const float4* pk = pack + (size_t)b * NPT;
  float4 q = pk[g & (NPT - 1)];
  float qx = q.x, qy = q.y, qz = q.z, qs = q.w;
  float bd[16];
  int bi[16];
#pragma unroll
  for (int j = 0; j < 16; ++j) { bd[j] = 1e30f; bi[j] = 0x7FFFFFFF; }
#pragma unroll 1
  for (int j = 0; j < 24; ++j) {
    int m = (int)(part[(size_t)j * NQ + g] & 0x1FFFu);  // coalesced
    float4 pm = pk[m];
    float dot = __fadd_rn(__fadd_rn(__fmul_rn(qx, pm.x), __fmul_rn(qy, pm.y)),
                          __fmul_rn(qz, pm.z));
    float kd = __fsub_rn(__fadd_rn(qs, pm.w), __fmul_rn(2.0f, dot));
    int ki = m;
    if (kd < bd[15] || (kd == bd[15] && ki < bi[15])) {  // guarded chain
#pragma unroll
      for (int qq = 0; qq < 16; ++qq) {
        bool cs = (kd < bd[qq]) || (kd == bd[qq] && ki < bi[qq]);
        float td = bd[qq];
        int ti = bi[qq];
        bd[qq] = cs ? kd : td;
        bi[qq] = cs ? ki : ti;
        kd = cs ? td : kd;
        ki = cs ? ti : ki;
      }
    }
  }
#pragma unroll
  for (int j = 0; j < 16; ++j) idxk[(size_t)g * 16 + j] = bi[j];
}

// ---------- feat: feat3T[P][0:64)=Gphi, [64:128)=Gpsi, [128:192)=alpha ----
__global__ __launch_bounds__(256) void feat_k(const float* __restrict__ features,
                                              const float* __restrict__ wcomb,
                                              float* __restrict__ feat3T) {
  int t = blockIdx.x * 256 + threadIdx.x;  // 65536
  int half = t >> 15;
  int P = t & 32767;
  int b = P >> 13, n = P & (NPT - 1);
  const float* fin = features + (size_t)b * 64 * NPT + n;
  float f[64];
#pragma unroll
  for (int c = 0; c < 64; ++c) f[c] = fin[(size_t)c * NPT];
  const float* W = wcomb + half * 96 * 64;
  float* op = feat3T + (size_t)P * 192 + half * 96;
  for (int r4 = 0; r4 < 24; ++r4) {
    float a0 = 0.f, a1 = 0.f, a2 = 0.f, a3 = 0.f;
    const float* w0 = W + (r4 * 4) * 64;
#pragma unroll
    for (int c = 0; c < 64; ++c) {
      a0 = fmaf(w0[c], f[c], a0);
      a1 = fmaf(w0[64 + c], f[c], a1);
      a2 = fmaf(w0[128 + c], f[c], a2);
      a3 = fmaf(w0[192 + c], f[c], a3);
    }
    *(float4*)(op + r4 * 4) = make_float4(a0, a1, a2, a3);
  }
}

// ---------- attention: 1 wave = 4 points; channel-split 64x32 LDS strip ---
#define SST2 33
__global__ __launch_bounds__(64) void attn_k(
    const float4* __restrict__ pack, const int* __restrict__ idxk,
    const float* __restrict__ feat3T, const float* __restrict__ G,
    const float* __restrict__ Mrow, const float* __restrict__ McT,
    float* __restrict__ out) {
  __shared__ float S[64 * SST2];
  int l = threadIdx.x;
  int Pb = blockIdx.x * 4;
  int b = Pb >> 13;
  int nb0 = Pb & (NPT - 1);
  int p = l >> 4;
  const float4* pkb = pack + (size_t)b * NPT;
  int idxv = idxk[(size_t)Pb * 16 + l];  // lane l = (point p, neighbor k)
  float4 own = pkb[nb0 + p];
  float4 nbr = pkb[idxv];
  float rx = own.x - nbr.x, ry = own.y - nbr.y, rz = own.z - nbr.z;
  float delta[64];
#pragma unroll
  for (int o = 0; o < 64; ++o)
    delta[o] = fmaxf(fmaf(Mrow[o * 3 + 2], rz, fmaf(Mrow[o * 3 + 1], ry, Mrow[o * 3] * rx)), 0.f);
  int c2 = l & 31, j2 = l >> 5;
  const float* phir = feat3T + (size_t)(Pb + p) * 192;
  const float* psir = feat3T + ((size_t)b * NPT + idxv) * 192 + 64;
#pragma unroll 1
  for (int pass = 0; pass < 2; ++pass) {
    // ---- write phase: channels [32*pass, 32*pass+32), row = pair lane ----
#pragma unroll
    for (int o4 = 0; o4 < 8; ++o4) {
      float4 ph = *(const float4*)(phir + pass * 32 + o4 * 4);
      float4 ps = *(const float4*)(psir + pass * 32 + o4 * 4);
      const float* gr = G + (pass * 32 + o4 * 4) * 64;
      float g0 = 0.f, g1 = 0.f, g2 = 0.f, g3 = 0.f;
#pragma unroll
      for (int c = 0; c < 64; ++c) {
        g0 = fmaf(gr[c], delta[c], g0);
        g1 = fmaf(gr[64 + c], delta[c], g1);
        g2 = fmaf(gr[128 + c], delta[c], g2);
        g3 = fmaf(gr[192 + c], delta[c], g3);
      }
      int ad = l * SST2 + o4 * 4;
      S[ad] = fmaxf(ph.x - ps.x + g0, 0.f);
      S[ad + 1] = fmaxf(ph.y - ps.y + g1, 0.f);
      S[ad + 2] = fmaxf(ph.z - ps.z + g2, 0.f);
      S[ad + 3] = fmaxf(ph.w - ps.w + g3, 0.f);
    }
    __syncthreads();
    // ---- read phase: lane = (j2, c2); 2 points per iteration -------------
    float m0v = McT[pass * 32 + c2];
    float m1v = McT[64 + pass * 32 + c2];
    float m2v = McT[128 + pass * 32 + c2];
#pragma unroll 1
    for (int jj = 0; jj < 2; ++jj) {
      int pj = jj * 2 + j2;
      int nj = nb0 + pj;
      float4 ownq = pkb[nj];
      float gvv[16];
      float mx = -1e30f;
#pragma unroll
      for (int r = 0; r < 16; ++r) {
        gvv[r] = S[(pj * 16 + r) * SST2 + c2];
        mx = fmaxf(mx, gvv[r]);
      }
      float s = 0.f;
#pragma unroll
      for (int r = 0; r < 16; ++r) {
        float e = __expf(gvv[r] - mx);
        gvv[r] = e;
        s += e;
      }
      float inv = 1.0f / s;
      float acc = 0.f;
#pragma unroll
      for (int r = 0; r < 16; ++r) {
        int si = __shfl(idxv, pj * 16 + r);
        float4 nbq = pkb[si];
        float dl = fmaxf(fmaf(m2v, ownq.z - nbq.z,
                              fmaf(m1v, ownq.y - nbq.y, m0v * (ownq.x - nbq.x))), 0.f);
        float al = feat3T[((size_t)b * NPT + si) * 192 + 128 + pass * 32 + c2];
        acc = fmaf(gvv[r] * inv, al + dl, acc);
      }
      out[(size_t)b * 64 * NPT + (size_t)(pass * 32 + c2) * NPT + nj] = acc;
    }
    __syncthreads();  // strip reused by next pass
  }
}

extern "C" void kernel_launch(void* const* d_in, const int* in_sizes, int n_in,
                              void* d_out, int out_size, void* d_ws, size_t ws_size,
                              hipStream_t stream) {
  const float* features = (const float*)d_in[0];
  const float* coords = (const float*)d_in[1];
  const float* w_lin = (const float*)d_in[2];
  const float* w_t1 = (const float*)d_in[3];
  const float* w_t2 = (const float*)d_in[4];
  const float* w_g1 = (const float*)d_in[5];
  const float* w_g2 = (const float*)d_in[6];
  float* out = (float*)d_out;
  char* ws = (char*)d_ws;
  // workspace layout (~26.9 MB total; part overlaps feat3T, consumed first)
  float4* pack = (float4*)ws;                   // 524288 B
  float* G = (float*)(ws + 524288);             // 16384 B
  float* Mrow = (float*)(ws + 540672);          // 768 B
  float* McT = (float*)(ws + 541440);           // 768 B
  float* wcomb = (float*)(ws + 542208);         // 49152 B
  int* idxk = (int*)(ws + 591360);              // 2 MB
  float* feat3T = (float*)(ws + 2688512);       // 24 MB
  u32* part = (u32*)(ws + 2688512);             // 3 MB (overlap, freed by refine)

  fold1_k<<<17, 256, 0, stream>>>(w_g1, w_g2, w_t1, w_t2, G, Mrow, McT);
  fold2_k<<<48, 256, 0, stream>>>(G, w_lin, wcomb);
  pack_k<<<128, 256, 0, stream>>>(coords, pack);
  knn_k<<<4096, 512, 0, stream>>>(pack, part);
  refine_k<<<128, 256, 0, stream>>>(pack, part, idxk);
  feat_k<<<256, 256, 0, stream>>>(features, wcomb, feat3T);  // after refine: reuses part region
  attn_k<<<8192, 64, 0, stream>>>(pack, idxk, feat3T, G, Mrow, McT, out);
}

// Round 8
// 410.946 us; speedup vs baseline: 2.3647x; 1.3279x over previous
//
#include <hip/hip_runtime.h>
#include <cstdint>

// PointTransformerLayer, MI355X. Folded-weight formulation:
//   M  = Wt2@Wt1 (64x3)          delta = relu(M . rel)
//   G  = Wg2@Wg1 (64x64)         g = relu(Gphi[n] - Gpsi[idx] + G.delta)
//   GW1= G@Wlin[0:64], GW2 = G@Wlin[64:128], alpha = Wlin[128:192] @ f
// KNN v3 (R7, unchanged): lane-parallel top-8 in regs + shfl merge top-24,
//   then numpy-fp32-bit-exact re-rank (no-FMA sequential fp32, stable ties).
// R8: attn G.delta moved to MFMA (mfma_f32_16x16x32_bf16, doc-verified
//   layouts: A m=lane&15,k=quad*8+j; C/D col=lane&15,row=quad*4+reg).
//   G prepacked to bf16 A-frags in fold2 (kills the per-wave G reload
//   storm); B-frags (u=relu(M.rel)) built in-register; epilogue fuses
//   pp=Gphi-Gpsi add + relu, dumps g bf16 to 8.7KB LDS; softmax/read
//   phase unchanged. Single-variable round: knn/refine/feat untouched.

#define NPT 8192
typedef unsigned long long u64;
typedef unsigned int u32;
typedef unsigned short u16;
typedef __attribute__((ext_vector_type(8))) short bf8_t;  // 8 bf16 (4 VGPR)
typedef __attribute__((ext_vector_type(4))) float f32x4;

__device__ __forceinline__ u16 f2bf(float x) {  // round-half-up bf16
  return (u16)((__float_as_uint(x) + 0x8000u) >> 16);
}
__device__ __forceinline__ u32 pkbf(float lo, float hi) {
  return (u32)f2bf(lo) | ((u32)f2bf(hi) << 16);
}

// ---------- fold1: G = Wg2@Wg1 (64x64); M = Wt2@Wt1 (64x3, row + colT) ----
__global__ __launch_bounds__(256) void fold1_k(
    const float* __restrict__ wg1, const float* __restrict__ wg2,
    const float* __restrict__ wt1, const float* __restrict__ wt2,
    float* __restrict__ G, float* __restrict__ Mrow, float* __restrict__ McT) {
  int t = blockIdx.x * 256 + threadIdx.x;
  if (t < 4096) {
    int o = t >> 6, c = t & 63;
    float acc = 0.f;
    for (int cp = 0; cp < 64; ++cp) acc = fmaf(wg2[o * 64 + cp], wg1[cp * 64 + c], acc);
    G[o * 64 + c] = acc;
  } else if (t < 4096 + 192) {
    int i = t - 4096;
    int o = i / 3, j = i - o * 3;
    float acc = 0.f;
    for (int c = 0; c < 64; ++c) acc = fmaf(wt2[o * 64 + c], wt1[c * 3 + j], acc);
    Mrow[o * 3 + j] = acc;
    McT[j * 64 + o] = acc;
  }
}

// ---------- fold2: wcomb + GF (G prepacked as bf16 MFMA A-frags) ----------
// GF[ot][kh][lane][j] = bf16(G[ot*16 + (lane&15)][kh*32 + (lane>>4)*8 + j])
__global__ __launch_bounds__(256) void fold2_k(
    const float* __restrict__ G, const float* __restrict__ wl,
    float* __restrict__ wcomb, u16* __restrict__ GF) {
  int t = blockIdx.x * 256 + threadIdx.x;  // 16384
  if (t < 12288) {
    int o = t >> 6, c = t & 63;
    float acc = 0.f;
    if (o < 64) {
      for (int cp = 0; cp < 64; ++cp) acc = fmaf(G[o * 64 + cp], wl[cp * 64 + c], acc);
    } else if (o < 128) {
      for (int cp = 0; cp < 64; ++cp) acc = fmaf(G[(o - 64) * 64 + cp], wl[(64 + cp) * 64 + c], acc);
    } else {
      acc = wl[o * 64 + c];
    }
    wcomb[o * 64 + c] = acc;
  } else if (t < 16384) {
    int i = t - 12288;
    int o = i >> 6, c = i & 63;
    int ot = o >> 4, m = o & 15;
    int kh = c >> 5, q = (c >> 3) & 3, j = c & 7;
    GF[(((ot * 2 + kh) * 64) + (q * 16 + m)) * 8 + j] = f2bf(G[o * 64 + c]);
  }
}

// ---------- pack coords as float4 (x,y,z,sq) with NP-EXACT sq -------------
__global__ __launch_bounds__(256) void pack_k(const float* __restrict__ coords,
                                              float4* __restrict__ pack) {
  int g = blockIdx.x * 256 + threadIdx.x;  // 32768
  int b = g >> 13, n = g & (NPT - 1);
  const float* c = coords + (size_t)b * 3 * NPT;
  float x = c[n], y = c[NPT + n], z = c[2 * NPT + n];
  float sq = __fadd_rn(__fadd_rn(__fmul_rn(x, x), __fmul_rn(y, y)), __fmul_rn(z, z));
  pack[g] = make_float4(x, y, z, sq);
}

// ---------- KNN v3: wave=query, per-lane reg top-8, wave merge top-24 -----
#define QPB 8
#define CHUNK 1024
#define NQ 32768
__global__ __launch_bounds__(512) void knn_k(const float4* __restrict__ pack,
                                             u32* __restrict__ part) {
  __shared__ float4 C[CHUNK];
  int tid = threadIdx.x;
  int w = tid >> 6, lane = tid & 63;
  int query = blockIdx.x * QPB + w;  // 4096 blocks
  int b = query >> 13, n = query & (NPT - 1);
  const float4* pk = pack + (size_t)b * NPT;
  float4 q = pk[n];
  float qsq = q.w;
  u32 arr[8];
#pragma unroll
  for (int j = 0; j < 8; ++j) arr[j] = 0xFFFFFFFFu;
  for (int c0 = 0; c0 < NPT; c0 += CHUNK) {
    C[tid] = pk[c0 + tid];
    C[tid + 512] = pk[c0 + tid + 512];
    __syncthreads();
#pragma unroll 4
    for (int t = 0; t < CHUNK / 64; ++t) {
      float4 c4 = C[t * 64 + lane];
      float dot = fmaf(q.z, c4.z, fmaf(q.y, c4.y, q.x * c4.x));
      float d2 = fmaxf(fmaf(-2.f, dot, qsq + c4.w), 0.f);
      u32 key = (__float_as_uint(d2) & 0xFFFFE000u) | (u32)(c0 + t * 64 + lane);
      if (key < arr[7]) {
#pragma unroll
        for (int qq = 0; qq < 8; ++qq) {
          u32 tt = arr[qq];
          arr[qq] = min(tt, key);
          key = max(tt, key);
        }
      }
    }
    __syncthreads();
  }
  u32 head = arr[0];
  u32 mg = 0xFFFFFFFFu;
#pragma unroll 1
  for (int r = 0; r < 24; ++r) {
    u32 m = head;
#pragma unroll
    for (int s = 1; s < 64; s <<= 1) m = min(m, (u32)__shfl_xor((int)m, s));
    if (lane == r) mg = m;
    if (head == m) {
      arr[0] = arr[1]; arr[1] = arr[2]; arr[2] = arr[3]; arr[3] = arr[4];
      arr[4] = arr[5]; arr[5] = arr[6]; arr[6] = arr[7]; arr[7] = 0xFFFFFFFFu;
      head = arr[0];
    }
  }
  if (lane < 24) part[(size_t)lane * NQ + query] = mg;
}

// ---------- numpy-fp32-bit-exact re-rank of the 24 survivors --------------
__global__ __launch_bounds__(256) void refine_k(const float4* __restrict__ pack,
                                                const u32* __restrict__ part,
                                                int* __restrict__ idxk) {
  int g = blockIdx.x * 256 + threadIdx.x;  // 32768
  int b = g >> 13;
  const float4* pk = pack + (size_t)b * NPT;
  float4 q = pk[g & (NPT - 1)];
  float qx = q.x, qy = q.y, qz = q.z, qs = q.w;
  float bd[16];
  int bi[16];
#pragma unroll
  for (int j = 0; j < 16; ++j) { bd[j] = 1e30f; bi[j] = 0x7FFFFFFF; }
#pragma unroll 1
  for (int j = 0; j < 24; ++j) {
    int m = (int)(part[(size_t)j * NQ + g] & 0x1FFFu);
    float4 pm = pk[m];
    float dot = __fadd_rn(__fadd_rn(__fmul_rn(qx, pm.x), __fmul_rn(qy, pm.y)),
                          __fmul_rn(qz, pm.z));
    float kd = __fsub_rn(__fadd_rn(qs, pm.w), __fmul_rn(2.0f, dot));
    int ki = m;
    if (kd < bd[15] || (kd == bd[15] && ki < bi[15])) {
#pragma unroll
      for (int qq = 0; qq < 16; ++qq) {
        bool cs = (kd < bd[qq]) || (kd == bd[qq] && ki < bi[qq]);
        float td = bd[qq];
        int ti = bi[qq];
        bd[qq] = cs ? kd : td;
        bi[qq] = cs ? ki : ti;
        kd = cs ? td : kd;
        ki = cs ? ti : ki;
      }
    }
  }
#pragma unroll
  for (int j = 0; j < 16; ++j) idxk[(size_t)g * 16 + j] = bi[j];
}

// ---------- feat: feat3T[P][0:64)=Gphi, [64:128)=Gpsi, [128:192)=alpha ----
__global__ __launch_bounds__(256) void feat_k(const float* __restrict__ features,
                                              const float* __restrict__ wcomb,
                                              float* __restrict__ feat3T) {
  int t = blockIdx.x * 256 + threadIdx.x;  // 65536
  int half = t >> 15;
  int P = t & 32767;
  int b = P >> 13, n = P & (NPT - 1);
  const float* fin = features + (size_t)b * 64 * NPT + n;
  float f[64];
#pragma unroll
  for (int c = 0; c < 64; ++c) f[c] = fin[(size_t)c * NPT];
  const float* W = wcomb + half * 96 * 64;
  float* op = feat3T + (size_t)P * 192 + half * 96;
  for (int r4 = 0; r4 < 24; ++r4) {
    float a0 = 0.f, a1 = 0.f, a2 = 0.f, a3 = 0.f;
    const float* w0 = W + (r4 * 4) * 64;
#pragma unroll
    for (int c = 0; c < 64; ++c) {
      a0 = fmaf(w0[c], f[c], a0);
      a1 = fmaf(w0[64 + c], f[c], a1);
      a2 = fmaf(w0[128 + c], f[c], a2);
      a3 = fmaf(w0[192 + c], f[c], a3);
    }
    *(float4*)(op + r4 * 4) = make_float4(a0, a1, a2, a3);
  }
}

// ---------- attention v2: MFMA G.delta core ------------------------------
// Wave = 4 points x 16 nbrs = 64 pairs. D[o][p] = G.u via 32 MFMA
// (4 o-tiles x 4 p-tiles x K=64). Epilogue fuses pp=Gphi-Gpsi, relu,
// dumps g (bf16) to LDS [pair][68] strip; read phase = softmax + gather.
#define SROW 68
__global__ __launch_bounds__(64) void attn_k(
    const float4* __restrict__ pack, const int* __restrict__ idxk,
    const float* __restrict__ feat3T, const u16* __restrict__ GF,
    const float* __restrict__ Mrow, const float* __restrict__ McT,
    float* __restrict__ out) {
  __shared__ u16 S16[64 * SROW];
  int l = threadIdx.x;
  int quad = l >> 4, col = l & 15;
  int Pb = blockIdx.x * 4;
  int b = Pb >> 13;
  int nb0 = Pb & (NPT - 1);
  const float4* pkb = pack + (size_t)b * NPT;
  int idxv = idxk[(size_t)Pb * 16 + l];  // lane l = (point l>>4, nbr l&15)
  // per p-tile neighbor index for column `col` (uniform control flow)
  int mve[4];
#pragma unroll
  for (int t = 0; t < 4; ++t) mve[t] = __shfl(idxv, t * 16 + col);
  // rel vectors for B-frags: pair p' = pt*16+col -> point nb0+pt, nbr mve[pt]
  float relx[4], rely[4], relz[4];
#pragma unroll
  for (int t = 0; t < 4; ++t) {
    float4 own = pkb[nb0 + t];
    float4 nbr = pkb[mve[t]];
    relx[t] = own.x - nbr.x; rely[t] = own.y - nbr.y; relz[t] = own.z - nbr.z;
  }
  // B-frags: u[k=kh*32+quad*8+j][p'=pt*16+col] = relu(M.rel), bf16
  bf8_t Bf[4][2];
#pragma unroll
  for (int kh = 0; kh < 2; ++kh) {
    const float* mr = Mrow + (kh * 32 + quad * 8) * 3;  // 8 rows x 3, aligned
    float m_[24];
#pragma unroll
    for (int i6 = 0; i6 < 6; ++i6) {
      float4 v = *(const float4*)(mr + i6 * 4);
      m_[i6 * 4] = v.x; m_[i6 * 4 + 1] = v.y; m_[i6 * 4 + 2] = v.z; m_[i6 * 4 + 3] = v.w;
    }
#pragma unroll
    for (int t = 0; t < 4; ++t) {
      float u_[8];
#pragma unroll
      for (int j = 0; j < 8; ++j)
        u_[j] = fmaxf(fmaf(m_[j * 3 + 2], relz[t],
                           fmaf(m_[j * 3 + 1], rely[t], m_[j * 3] * relx[t])), 0.f);
      union { u32 w[4]; bf8_t v; } ub;
#pragma unroll
      for (int j2 = 0; j2 < 4; ++j2) ub.w[j2] = pkbf(u_[j2 * 2], u_[j2 * 2 + 1]);
      Bf[t][kh] = ub.v;
    }
  }
  // MFMA + fused epilogue (acc tile lives 8 regs at a time)
  const bf8_t* gfr = (const bf8_t*)GF;
#pragma unroll
  for (int ot = 0; ot < 4; ++ot) {
    bf8_t A0 = gfr[(ot * 2 + 0) * 64 + l];
    bf8_t A1 = gfr[(ot * 2 + 1) * 64 + l];
#pragma unroll
    for (int pt = 0; pt < 4; ++pt) {
      f32x4 acc = {0.f, 0.f, 0.f, 0.f};
      acc = __builtin_amdgcn_mfma_f32_16x16x32_bf16(A0, Bf[pt][0], acc, 0, 0, 0);
      acc = __builtin_amdgcn_mfma_f32_16x16x32_bf16(A1, Bf[pt][1], acc, 0, 0, 0);
      // o = ot*16 + quad*4 + r ; pair p' = pt*16 + col
      const float* phn = feat3T + (size_t)(Pb + pt) * 192 + ot * 16 + quad * 4;
      const float* psn = feat3T + ((size_t)b * NPT + mve[pt]) * 192 + 64 + ot * 16 + quad * 4;
      float4 ph = *(const float4*)phn;
      float4 ps = *(const float4*)psn;
      float g0 = fmaxf(acc[0] + ph.x - ps.x, 0.f);
      float g1 = fmaxf(acc[1] + ph.y - ps.y, 0.f);
      float g2 = fmaxf(acc[2] + ph.z - ps.z, 0.f);
      float g3 = fmaxf(acc[3] + ph.w - ps.w, 0.f);
      uint2 wv = make_uint2(pkbf(g0, g1), pkbf(g2, g3));
      *(uint2*)&S16[(pt * 16 + col) * SROW + ot * 16 + quad * 4] = wv;
    }
  }
  __syncthreads();  // publish g strip to whole wave
  // read phase: lane = (j2, c2); softmax over k + weighted sum (fp32)
  int c2 = l & 31, j2 = l >> 5;
#pragma unroll 1
  for (int pass = 0; pass < 2; ++pass) {
    float m0v = McT[pass * 32 + c2];
    float m1v = McT[64 + pass * 32 + c2];
    float m2v = McT[128 + pass * 32 + c2];
#pragma unroll 1
    for (int jj = 0; jj < 2; ++jj) {
      int pj = jj * 2 + j2;
      int nj = nb0 + pj;
      float4 ownq = pkb[nj];
      float gvv[16];
      float mx = -1e30f;
#pragma unroll
      for (int r = 0; r < 16; ++r) {
        gvv[r] = __uint_as_float((u32)S16[(pj * 16 + r) * SROW + pass * 32 + c2] << 16);
        mx = fmaxf(mx, gvv[r]);
      }
      float s = 0.f;
#pragma unroll
      for (int r = 0; r < 16; ++r) {
        float e = __expf(gvv[r] - mx);
        gvv[r] = e;
        s += e;
      }
      float inv = 1.0f / s;
      float acc = 0.f;
#pragma unroll
      for (int r = 0; r < 16; ++r) {
        int si = __shfl(idxv, pj * 16 + r);
        float4 nbq = pkb[si];
        float dl = fmaxf(fmaf(m2v, ownq.z - nbq.z,
                              fmaf(m1v, ownq.y - nbq.y, m0v * (ownq.x - nbq.x))), 0.f);
        float al = feat3T[((size_t)b * NPT + si) * 192 + 128 + pass * 32 + c2];
        acc = fmaf(gvv[r] * inv, al + dl, acc);
      }
      out[(size_t)b * 64 * NPT + (size_t)(pass * 32 + c2) * NPT + nj] = acc;
    }
  }
}

extern "C" void kernel_launch(void* const* d_in, const int* in_sizes, int n_in,
                              void* d_out, int out_size, void* d_ws, size_t ws_size,
                              hipStream_t stream) {
  const float* features = (const float*)d_in[0];
  const float* coords = (const float*)d_in[1];
  const float* w_lin = (const float*)d_in[2];
  const float* w_t1 = (const float*)d_in[3];
  const float* w_t2 = (const float*)d_in[4];
  const float* w_g1 = (const float*)d_in[5];
  const float* w_g2 = (const float*)d_in[6];
  float* out = (float*)d_out;
  char* ws = (char*)d_ws;
  // workspace layout (~27.9 MB; part overlaps feat3T, consumed by refine)
  float4* pack = (float4*)ws;                   // 524288 B
  float* G = (float*)(ws + 524288);             // 16384 B
  float* Mrow = (float*)(ws + 540672);          // 768 B
  float* McT = (float*)(ws + 541440);           // 768 B
  float* wcomb = (float*)(ws + 542208);         // 49152 B
  int* idxk = (int*)(ws + 591360);              // 2 MB
  float* feat3T = (float*)(ws + 2688512);       // 24 MB
  u32* part = (u32*)(ws + 2688512);             // 3 MB (overlap, freed by refine)
  u16* GF = (u16*)(ws + 27854336);              // 8 KB bf16 A-frags

  fold1_k<<<17, 256, 0, stream>>>(w_g1, w_g2, w_t1, w_t2, G, Mrow, McT);
  fold2_k<<<64, 256, 0, stream>>>(G, w_lin, wcomb, GF);
  pack_k<<<128, 256, 0, stream>>>(coords, pack);
  knn_k<<<4096, 512, 0, stream>>>(pack, part);
  refine_k<<<128, 256, 0, stream>>>(pack, part, idxk);
  feat_k<<<256, 256, 0, stream>>>(features, wcomb, feat3T);  // reuses part region
  attn_k<<<8192, 64, 0, stream>>>(pack, idxk, feat3T, GF, Mrow, McT, out);
}

// Round 9
// 359.413 us; speedup vs baseline: 2.7037x; 1.1434x over previous
//
#include <hip/hip_runtime.h>
#include <cstdint>

// PointTransformerLayer, MI355X. Folded-weight formulation:
//   M  = Wt2@Wt1 (64x3)          delta = relu(M . rel)
//   G  = Wg2@Wg1 (64x64)         g = relu(Gphi[n] - Gpsi[idx] + G.delta)
//   GW1= G@Wlin[0:64], GW2 = G@Wlin[64:128], alpha = Wlin[128:192] @ f
// KNN v3: lane-parallel top-8 in regs + shfl merge top-24, then
//   numpy-fp32-bit-exact re-rank (no-FMA sequential fp32, stable ties).
// R9: (a) knn insertion chain via v_med3_u32 (sorted-insert-drop-max ==
//   med3(key, a[i-1], a[i]) descending; 8 instr vs 16 min/max — the chain
//   issues at wave-OR P~1, structural, so instr count is the lever);
//   (b) feat payload split: featA = Gphi fp32 (coalesced loads),
//   featB = Gpsi+alpha bf16 (random gathers halve in bytes). attn MFMA
//   core (R8, doc-verified layouts) unchanged.

#define NPT 8192
typedef unsigned long long u64;
typedef unsigned int u32;
typedef unsigned short u16;
typedef __attribute__((ext_vector_type(8))) short bf8_t;  // 8 bf16 (4 VGPR)
typedef __attribute__((ext_vector_type(4))) float f32x4;

__device__ __forceinline__ u16 f2bf(float x) {  // round-half-up bf16
  return (u16)((__float_as_uint(x) + 0x8000u) >> 16);
}
__device__ __forceinline__ u32 pkbf(float lo, float hi) {
  return (u32)f2bf(lo) | ((u32)f2bf(hi) << 16);
}
__device__ __forceinline__ float bf2f(u16 v) {
  return __uint_as_float((u32)v << 16);
}
__device__ __forceinline__ u32 med3u(u32 a, u32 b, u32 c) {
  u32 d;
  asm("v_med3_u32 %0, %1, %2, %3" : "=v"(d) : "v"(a), "v"(b), "v"(c));
  return d;
}

// ---------- fold1: G = Wg2@Wg1 (64x64); M = Wt2@Wt1 (64x3, row + colT) ----
__global__ __launch_bounds__(256) void fold1_k(
    const float* __restrict__ wg1, const float* __restrict__ wg2,
    const float* __restrict__ wt1, const float* __restrict__ wt2,
    float* __restrict__ G, float* __restrict__ Mrow, float* __restrict__ McT) {
  int t = blockIdx.x * 256 + threadIdx.x;
  if (t < 4096) {
    int o = t >> 6, c = t & 63;
    float acc = 0.f;
    for (int cp = 0; cp < 64; ++cp) acc = fmaf(wg2[o * 64 + cp], wg1[cp * 64 + c], acc);
    G[o * 64 + c] = acc;
  } else if (t < 4096 + 192) {
    int i = t - 4096;
    int o = i / 3, j = i - o * 3;
    float acc = 0.f;
    for (int c = 0; c < 64; ++c) acc = fmaf(wt2[o * 64 + c], wt1[c * 3 + j], acc);
    Mrow[o * 3 + j] = acc;
    McT[j * 64 + o] = acc;
  }
}

// ---------- fold2: wcomb + GF (G prepacked as bf16 MFMA A-frags) ----------
__global__ __launch_bounds__(256) void fold2_k(
    const float* __restrict__ G, const float* __restrict__ wl,
    float* __restrict__ wcomb, u16* __restrict__ GF) {
  int t = blockIdx.x * 256 + threadIdx.x;  // 16384
  if (t < 12288) {
    int o = t >> 6, c = t & 63;
    float acc = 0.f;
    if (o < 64) {
      for (int cp = 0; cp < 64; ++cp) acc = fmaf(G[o * 64 + cp], wl[cp * 64 + c], acc);
    } else if (o < 128) {
      for (int cp = 0; cp < 64; ++cp) acc = fmaf(G[(o - 64) * 64 + cp], wl[(64 + cp) * 64 + c], acc);
    } else {
      acc = wl[o * 64 + c];
    }
    wcomb[o * 64 + c] = acc;
  } else if (t < 16384) {
    int i = t - 12288;
    int o = i >> 6, c = i & 63;
    int ot = o >> 4, m = o & 15;
    int kh = c >> 5, q = (c >> 3) & 3, j = c & 7;
    GF[(((ot * 2 + kh) * 64) + (q * 16 + m)) * 8 + j] = f2bf(G[o * 64 + c]);
  }
}

// ---------- pack coords as float4 (x,y,z,sq) with NP-EXACT sq -------------
__global__ __launch_bounds__(256) void pack_k(const float* __restrict__ coords,
                                              float4* __restrict__ pack) {
  int g = blockIdx.x * 256 + threadIdx.x;  // 32768
  int b = g >> 13, n = g & (NPT - 1);
  const float* c = coords + (size_t)b * 3 * NPT;
  float x = c[n], y = c[NPT + n], z = c[2 * NPT + n];
  float sq = __fadd_rn(__fadd_rn(__fmul_rn(x, x), __fmul_rn(y, y)), __fmul_rn(z, z));
  pack[g] = make_float4(x, y, z, sq);
}

// ---------- KNN v3: wave=query, per-lane reg top-8 (med3 chain) -----------
#define QPB 8
#define CHUNK 1024
#define NQ 32768
__global__ __launch_bounds__(512) void knn_k(const float4* __restrict__ pack,
                                             u32* __restrict__ part) {
  __shared__ float4 C[CHUNK];
  int tid = threadIdx.x;
  int w = tid >> 6, lane = tid & 63;
  int query = blockIdx.x * QPB + w;  // 4096 blocks
  int b = query >> 13, n = query & (NPT - 1);
  const float4* pk = pack + (size_t)b * NPT;
  float4 q = pk[n];
  float qsq = q.w;
  u32 arr[8];
#pragma unroll
  for (int j = 0; j < 8; ++j) arr[j] = 0xFFFFFFFFu;
  for (int c0 = 0; c0 < NPT; c0 += CHUNK) {
    C[tid] = pk[c0 + tid];
    C[tid + 512] = pk[c0 + tid + 512];
    __syncthreads();
#pragma unroll 4
    for (int t = 0; t < CHUNK / 64; ++t) {
      float4 c4 = C[t * 64 + lane];
      float dot = fmaf(q.z, c4.z, fmaf(q.y, c4.y, q.x * c4.x));
      float d2 = fmaxf(fmaf(-2.f, dot, qsq + c4.w), 0.f);
      u32 key = (__float_as_uint(d2) & 0xFFFFE000u) | (u32)(c0 + t * 64 + lane);
      if (key < arr[7]) {  // sorted-insert-drop-max: 1 med3 per slot
        arr[7] = med3u(key, arr[6], arr[7]);
        arr[6] = med3u(key, arr[5], arr[6]);
        arr[5] = med3u(key, arr[4], arr[5]);
        arr[4] = med3u(key, arr[3], arr[4]);
        arr[3] = med3u(key, arr[2], arr[3]);
        arr[2] = med3u(key, arr[1], arr[2]);
        arr[1] = med3u(key, arr[0], arr[1]);
        arr[0] = min(arr[0], key);
      }
    }
    __syncthreads();
  }
  u32 head = arr[0];
  u32 mg = 0xFFFFFFFFu;
#pragma unroll 1
  for (int r = 0; r < 24; ++r) {
    u32 m = head;
#pragma unroll
    for (int s = 1; s < 64; s <<= 1) m = min(m, (u32)__shfl_xor((int)m, s));
    if (lane == r) mg = m;
    if (head == m) {
      arr[0] = arr[1]; arr[1] = arr[2]; arr[2] = arr[3]; arr[3] = arr[4];
      arr[4] = arr[5]; arr[5] = arr[6]; arr[6] = arr[7]; arr[7] = 0xFFFFFFFFu;
      head = arr[0];
    }
  }
  if (lane < 24) part[(size_t)lane * NQ + query] = mg;
}

// ---------- numpy-fp32-bit-exact re-rank of the 24 survivors --------------
__global__ __launch_bounds__(256) void refine_k(const float4* __restrict__ pack,
                                                const u32* __restrict__ part,
                                                int* __restrict__ idxk) {
  int g = blockIdx.x * 256 + threadIdx.x;  // 32768
  int b = g >> 13;
  const float4* pk = pack + (size_t)b * NPT;
  float4 q = pk[g & (NPT - 1)];
  float qx = q.x, qy = q.y, qz = q.z, qs = q.w;
  float bd[16];
  int bi[16];
#pragma unroll
  for (int j = 0; j < 16; ++j) { bd[j] = 1e30f; bi[j] = 0x7FFFFFFF; }
#pragma unroll 1
  for (int j = 0; j < 24; ++j) {
    int m = (int)(part[(size_t)j * NQ + g] & 0x1FFFu);
    float4 pm = pk[m];
    float dot = __fadd_rn(__fadd_rn(__fmul_rn(qx, pm.x), __fmul_rn(qy, pm.y)),
                          __fmul_rn(qz, pm.z));
    float kd = __fsub_rn(__fadd_rn(qs, pm.w), __fmul_rn(2.0f, dot));
    int ki = m;
    if (kd < bd[15] || (kd == bd[15] && ki < bi[15])) {
#pragma unroll
      for (int qq = 0; qq < 16; ++qq) {
        bool cs = (kd < bd[qq]) || (kd == bd[qq] && ki < bi[qq]);
        float td = bd[qq];
        int ti = bi[qq];
        bd[qq] = cs ? kd : td;
        bi[qq] = cs ? ki : ti;
        kd = cs ? td : kd;
        ki = cs ? ti : ki;
      }
    }
  }
#pragma unroll
  for (int j = 0; j < 16; ++j) idxk[(size_t)g * 16 + j] = bi[j];
}

// ---------- feat: featA[P][64]=Gphi fp32; featB[P][128]=Gpsi|alpha bf16 ---
__global__ __launch_bounds__(256) void feat_k(const float* __restrict__ features,
                                              const float* __restrict__ wcomb,
                                              float* __restrict__ featA,
                                              u16* __restrict__ featB) {
  int t = blockIdx.x * 256 + threadIdx.x;  // 65536
  int half = t >> 15;
  int P = t & 32767;
  int b = P >> 13, n = P & (NPT - 1);
  const float* fin = features + (size_t)b * 64 * NPT + n;
  float f[64];
#pragma unroll
  for (int c = 0; c < 64; ++c) f[c] = fin[(size_t)c * NPT];
  const float* W = wcomb + half * 96 * 64;
  for (int r4 = 0; r4 < 24; ++r4) {
    float a0 = 0.f, a1 = 0.f, a2 = 0.f, a3 = 0.f;
    const float* w0 = W + (r4 * 4) * 64;
#pragma unroll
    for (int c = 0; c < 64; ++c) {
      a0 = fmaf(w0[c], f[c], a0);
      a1 = fmaf(w0[64 + c], f[c], a1);
      a2 = fmaf(w0[128 + c], f[c], a2);
      a3 = fmaf(w0[192 + c], f[c], a3);
    }
    int gr = half * 96 + r4 * 4;  // global output row
    if (gr < 64) {
      *(float4*)(featA + (size_t)P * 64 + gr) = make_float4(a0, a1, a2, a3);
    } else {
      uint2 wv = make_uint2(pkbf(a0, a1), pkbf(a2, a3));
      *(uint2*)(featB + (size_t)P * 128 + (gr - 64)) = wv;
    }
  }
}

// ---------- attention v2: MFMA G.delta core, bf16 psi/alpha gathers -------
#define SROW 68
__global__ __launch_bounds__(64) void attn_k(
    const float4* __restrict__ pack, const int* __restrict__ idxk,
    const float* __restrict__ featA, const u16* __restrict__ featB,
    const u16* __restrict__ GF, const float* __restrict__ Mrow,
    const float* __restrict__ McT, float* __restrict__ out) {
  __shared__ u16 S16[64 * SROW];
  int l = threadIdx.x;
  int quad = l >> 4, col = l & 15;
  int Pb = blockIdx.x * 4;
  int b = Pb >> 13;
  int nb0 = Pb & (NPT - 1);
  const float4* pkb = pack + (size_t)b * NPT;
  int idxv = idxk[(size_t)Pb * 16 + l];  // lane l = (point l>>4, nbr l&15)
  int mve[4];
#pragma unroll
  for (int t = 0; t < 4; ++t) mve[t] = __shfl(idxv, t * 16 + col);
  float relx[4], rely[4], relz[4];
#pragma unroll
  for (int t = 0; t < 4; ++t) {
    float4 own = pkb[nb0 + t];
    float4 nbr = pkb[mve[t]];
    relx[t] = own.x - nbr.x; rely[t] = own.y - nbr.y; relz[t] = own.z - nbr.z;
  }
  // B-frags: u[k=kh*32+quad*8+j][p'=pt*16+col] = relu(M.rel), bf16
  bf8_t Bf[4][2];
#pragma unroll
  for (int kh = 0; kh < 2; ++kh) {
    const float* mr = Mrow + (kh * 32 + quad * 8) * 3;
    float m_[24];
#pragma unroll
    for (int i6 = 0; i6 < 6; ++i6) {
      float4 v = *(const float4*)(mr + i6 * 4);
      m_[i6 * 4] = v.x; m_[i6 * 4 + 1] = v.y; m_[i6 * 4 + 2] = v.z; m_[i6 * 4 + 3] = v.w;
    }
#pragma unroll
    for (int t = 0; t < 4; ++t) {
      float u_[8];
#pragma unroll
      for (int j = 0; j < 8; ++j)
        u_[j] = fmaxf(fmaf(m_[j * 3 + 2], relz[t],
                           fmaf(m_[j * 3 + 1], rely[t], m_[j * 3] * relx[t])), 0.f);
      union { u32 w[4]; bf8_t v; } ub;
#pragma unroll
      for (int j2 = 0; j2 < 4; ++j2) ub.w[j2] = pkbf(u_[j2 * 2], u_[j2 * 2 + 1]);
      Bf[t][kh] = ub.v;
    }
  }
  // MFMA + fused epilogue
  const bf8_t* gfr = (const bf8_t*)GF;
#pragma unroll
  for (int ot = 0; ot < 4; ++ot) {
    bf8_t A0 = gfr[(ot * 2 + 0) * 64 + l];
    bf8_t A1 = gfr[(ot * 2 + 1) * 64 + l];
#pragma unroll
    for (int pt = 0; pt < 4; ++pt) {
      f32x4 acc = {0.f, 0.f, 0.f, 0.f};
      acc = __builtin_amdgcn_mfma_f32_16x16x32_bf16(A0, Bf[pt][0], acc, 0, 0, 0);
      acc = __builtin_amdgcn_mfma_f32_16x16x32_bf16(A1, Bf[pt][1], acc, 0, 0, 0);
      // o = ot*16 + quad*4 + r ; pair p' = pt*16 + col
      const float* phn = featA + (size_t)(Pb + pt) * 64 + ot * 16 + quad * 4;
      float4 ph = *(const float4*)phn;
      uint2 psw = *(const uint2*)(featB + ((size_t)b * NPT + mve[pt]) * 128 + ot * 16 + quad * 4);
      float g0 = fmaxf(acc[0] + ph.x - bf2f((u16)(psw.x & 0xFFFF)), 0.f);
      float g1 = fmaxf(acc[1] + ph.y - bf2f((u16)(psw.x >> 16)), 0.f);
      float g2 = fmaxf(acc[2] + ph.z - bf2f((u16)(psw.y & 0xFFFF)), 0.f);
      float g3 = fmaxf(acc[3] + ph.w - bf2f((u16)(psw.y >> 16)), 0.f);
      uint2 wv = make_uint2(pkbf(g0, g1), pkbf(g2, g3));
      *(uint2*)&S16[(pt * 16 + col) * SROW + ot * 16 + quad * 4] = wv;
    }
  }
  __syncthreads();  // publish g strip to whole wave
  // read phase: lane = (j2, c2); softmax over k + weighted sum (fp32)
  int c2 = l & 31, j2 = l >> 5;
#pragma unroll 1
  for (int pass = 0; pass < 2; ++pass) {
    float m0v = McT[pass * 32 + c2];
    float m1v = McT[64 + pass * 32 + c2];
    float m2v = McT[128 + pass * 32 + c2];
#pragma unroll 1
    for (int jj = 0; jj < 2; ++jj) {
      int pj = jj * 2 + j2;
      int nj = nb0 + pj;
      float4 ownq = pkb[nj];
      float gvv[16];
      float mx = -1e30f;
#pragma unroll
      for (int r = 0; r < 16; ++r) {
        gvv[r] = bf2f(S16[(pj * 16 + r) * SROW + pass * 32 + c2]);
        mx = fmaxf(mx, gvv[r]);
      }
      float s = 0.f;
#pragma unroll
      for (int r = 0; r < 16; ++r) {
        float e = __expf(gvv[r] - mx);
        gvv[r] = e;
        s += e;
      }
      float inv = 1.0f / s;
      float acc = 0.f;
#pragma unroll
      for (int r = 0; r < 16; ++r) {
        int si = __shfl(idxv, pj * 16 + r);
        float4 nbq = pkb[si];
        float dl = fmaxf(fmaf(m2v, ownq.z - nbq.z,
                              fmaf(m1v, ownq.y - nbq.y, m0v * (ownq.x - nbq.x))), 0.f);
        float al = bf2f(featB[((size_t)b * NPT + si) * 128 + 64 + pass * 32 + c2]);
        acc = fmaf(gvv[r] * inv, al + dl, acc);
      }
      out[(size_t)b * 64 * NPT + (size_t)(pass * 32 + c2) * NPT + nj] = acc;
    }
  }
}

extern "C" void kernel_launch(void* const* d_in, const int* in_sizes, int n_in,
                              void* d_out, int out_size, void* d_ws, size_t ws_size,
                              hipStream_t stream) {
  const float* features = (const float*)d_in[0];
  const float* coords = (const float*)d_in[1];
  const float* w_lin = (const float*)d_in[2];
  const float* w_t1 = (const float*)d_in[3];
  const float* w_t2 = (const float*)d_in[4];
  const float* w_g1 = (const float*)d_in[5];
  const float* w_g2 = (const float*)d_in[6];
  float* out = (float*)d_out;
  char* ws = (char*)d_ws;
  // workspace layout (~19.5 MB; part overlaps featA, consumed by refine)
  float4* pack = (float4*)ws;                   // 524288 B
  float* G = (float*)(ws + 524288);             // 16384 B
  float* Mrow = (float*)(ws + 540672);          // 768 B
  float* McT = (float*)(ws + 541440);           // 768 B
  float* wcomb = (float*)(ws + 542208);         // 49152 B
  int* idxk = (int*)(ws + 591360);              // 2 MB
  float* featA = (float*)(ws + 2688512);        // 8 MB fp32 Gphi
  u16* featB = (u16*)(ws + 11077120);           // 8 MB bf16 Gpsi|alpha
  u32* part = (u32*)(ws + 2688512);             // 3 MB (overlap, freed by refine)
  u16* GF = (u16*)(ws + 19465728);              // 8 KB bf16 A-frags

  fold1_k<<<17, 256, 0, stream>>>(w_g1, w_g2, w_t1, w_t2, G, Mrow, McT);
  fold2_k<<<64, 256, 0, stream>>>(G, w_lin, wcomb, GF);
  pack_k<<<128, 256, 0, stream>>>(coords, pack);
  knn_k<<<4096, 512, 0, stream>>>(pack, part);
  refine_k<<<128, 256, 0, stream>>>(pack, part, idxk);
  feat_k<<<256, 256, 0, stream>>>(features, wcomb, featA, featB);  // reuses part region
  attn_k<<<8192, 64, 0, stream>>>(pack, idxk, featA, featB, GF, Mrow, McT, out);
}